// Round 16
// baseline (117.474 us; speedup 1.0000x reference)
//
#include <hip/hip_runtime.h>

// FactorizedSpectralConv2d: B=16, CIN=COUT=64, H=W=128, MH=MW=32, super_res=1
// kAB (W-rDFT GEMM + folded H-DFT) -> kC (channel mix, global_load_lds async
// double-buffered staging) -> kDE (inv H-DFT folded + inv W-rDFT w-folded).
// ws layout (64 MiB): XF[48,64) ; YF0[0,16) ; YF1[16,32)

__device__ __forceinline__ void build_tab(float* tabs) {
    int t = threadIdx.x;
    if (t < 128) {
        float ang = (float)t * 0.049087385212340517f;  // 2*pi/128
        float s, c;
        sincosf(ang, &s, &c);
        tabs[t] = c;        // cos at [0..127]
        tabs[129 + t] = s;  // sin at [129..256]
    }
}

// ---- kAB: fused W-rDFT (per (b,ci) image) + folded H-DFT ------------------
__global__ __launch_bounds__(256) void kAB(const float* __restrict__ x,
                                           float* __restrict__ XF) {
    __shared__ float tabs[258];
    __shared__ __align__(16) float smem[8704];  // Twid[0,4096)|xeo[4096,8256); later Af[0,8704)
    build_tab(tabs);
    __syncthreads();
    int t = threadIdx.x;
    size_t bc = blockIdx.x;  // b*64+ci, 1024 blocks
    float* Twid = smem;
    float* xeo  = smem + 4096;
    #pragma unroll
    for (int i = 0; i < 16; ++i) {
        int e = t + i * 256;
        int w = e >> 6, q = e & 63, kx = q >> 1;
        int idx = (w * kx) & 127;
        Twid[e] = (q & 1) ? -tabs[129 + idx] : tabs[idx];
    }
    const float* xb = x + bc * 16384;
    int th = t & 31;   // h in {2th, 2th+1, 2th+64, 2th+65}
    int tq = t >> 5;   // q in [8tq, 8tq+8)
    int q0 = tq * 8;
    int wl4 = (t & 3) * 4;  // staging lanes
    int hb  = t >> 2;
    float4 rlo0, rhi0, rlo1, rhi1;
    auto loadR = [&](int ph) {
        rlo0 = *(const float4*)(xb + hb * 128 + ph * 16 + wl4);
        rhi0 = *(const float4*)(xb + hb * 128 + ph * 16 + wl4 + 64);
        rlo1 = *(const float4*)(xb + (64 + hb) * 128 + ph * 16 + wl4);
        rhi1 = *(const float4*)(xb + (64 + hb) * 128 + ph * 16 + wl4 + 64);
    };
    auto writeR = [&]() {
        int h0 = hb, h1 = 64 + hb;
        *(float2*)(&xeo[(wl4+0)*260 + 2*h0]) = make_float2(rlo0.x+rhi0.x, rlo0.x-rhi0.x);
        *(float2*)(&xeo[(wl4+1)*260 + 2*h0]) = make_float2(rlo0.y+rhi0.y, rlo0.y-rhi0.y);
        *(float2*)(&xeo[(wl4+2)*260 + 2*h0]) = make_float2(rlo0.z+rhi0.z, rlo0.z-rhi0.z);
        *(float2*)(&xeo[(wl4+3)*260 + 2*h0]) = make_float2(rlo0.w+rhi0.w, rlo0.w-rhi0.w);
        *(float2*)(&xeo[(wl4+0)*260 + 2*h1]) = make_float2(rlo1.x+rhi1.x, rlo1.x-rhi1.x);
        *(float2*)(&xeo[(wl4+1)*260 + 2*h1]) = make_float2(rlo1.y+rhi1.y, rlo1.y-rhi1.y);
        *(float2*)(&xeo[(wl4+2)*260 + 2*h1]) = make_float2(rlo1.z+rhi1.z, rlo1.z-rhi1.z);
        *(float2*)(&xeo[(wl4+3)*260 + 2*h1]) = make_float2(rlo1.w+rhi1.w, rlo1.w-rhi1.w);
    };
    loadR(0);
    writeR();
    float4 acc[8];
    #pragma unroll
    for (int j = 0; j < 8; ++j) acc[j] = make_float4(0.f, 0.f, 0.f, 0.f);
    __syncthreads();  // xeo(0) ready
    for (int ph = 0; ph < 4; ++ph) {
        if (ph < 3) loadR(ph + 1);  // loads fly under compute
        #pragma unroll 4
        for (int wl = 0; wl < 16; ++wl) {
            int w = ph * 16 + wl;
            const float* xr = &xeo[wl * 260 + 4 * th];
            float4 d0  = *(const float4*)(xr);         // ve,vo for h=2th, 2th+1
            float4 d1  = *(const float4*)(xr + 128);   // ve,vo for h+64
            float4 tw0 = *(const float4*)(&Twid[w * 64 + q0]);
            float4 tw1 = *(const float4*)(&Twid[w * 64 + q0 + 4]);
            acc[0].x = fmaf(d0.x, tw0.x, acc[0].x); acc[0].y = fmaf(d0.x, tw0.y, acc[0].y);
            acc[0].z = fmaf(d0.y, tw0.z, acc[0].z); acc[0].w = fmaf(d0.y, tw0.w, acc[0].w);
            acc[1].x = fmaf(d0.x, tw1.x, acc[1].x); acc[1].y = fmaf(d0.x, tw1.y, acc[1].y);
            acc[1].z = fmaf(d0.y, tw1.z, acc[1].z); acc[1].w = fmaf(d0.y, tw1.w, acc[1].w);
            acc[2].x = fmaf(d0.z, tw0.x, acc[2].x); acc[2].y = fmaf(d0.z, tw0.y, acc[2].y);
            acc[2].z = fmaf(d0.w, tw0.z, acc[2].z); acc[2].w = fmaf(d0.w, tw0.w, acc[2].w);
            acc[3].x = fmaf(d0.z, tw1.x, acc[3].x); acc[3].y = fmaf(d0.z, tw1.y, acc[3].y);
            acc[3].z = fmaf(d0.w, tw1.z, acc[3].z); acc[3].w = fmaf(d0.w, tw1.w, acc[3].w);
            acc[4].x = fmaf(d1.x, tw0.x, acc[4].x); acc[4].y = fmaf(d1.x, tw0.y, acc[4].y);
            acc[4].z = fmaf(d1.y, tw0.z, acc[4].z); acc[4].w = fmaf(d1.y, tw0.w, acc[4].w);
            acc[5].x = fmaf(d1.x, tw1.x, acc[5].x); acc[5].y = fmaf(d1.x, tw1.y, acc[5].y);
            acc[5].z = fmaf(d1.y, tw1.z, acc[5].z); acc[5].w = fmaf(d1.y, tw1.w, acc[5].w);
            acc[6].x = fmaf(d1.z, tw0.x, acc[6].x); acc[6].y = fmaf(d1.z, tw0.y, acc[6].y);
            acc[6].z = fmaf(d1.w, tw0.z, acc[6].z); acc[6].w = fmaf(d1.w, tw0.w, acc[6].w);
            acc[7].x = fmaf(d1.z, tw1.x, acc[7].x); acc[7].y = fmaf(d1.z, tw1.y, acc[7].y);
            acc[7].z = fmaf(d1.w, tw1.z, acc[7].z); acc[7].w = fmaf(d1.w, tw1.w, acc[7].w);
        }
        __syncthreads();
        if (ph < 3) {
            writeR();
            __syncthreads();
        }
    }
    // In-register (h, h+64) fold -> Af planes, row stride 68.
    float* Af = smem;
    {
        int base = th * 68 + q0;
        *(float4*)(&Af[base])          = make_float4(acc[0].x+acc[4].x, acc[0].y+acc[4].y, acc[0].z+acc[4].z, acc[0].w+acc[4].w);
        *(float4*)(&Af[base + 4])      = make_float4(acc[1].x+acc[5].x, acc[1].y+acc[5].y, acc[1].z+acc[5].z, acc[1].w+acc[5].w);
        *(float4*)(&Af[2176 + base])   = make_float4(acc[0].x-acc[4].x, acc[0].y-acc[4].y, acc[0].z-acc[4].z, acc[0].w-acc[4].w);
        *(float4*)(&Af[2176 + base+4]) = make_float4(acc[1].x-acc[5].x, acc[1].y-acc[5].y, acc[1].z-acc[5].z, acc[1].w-acc[5].w);
        *(float4*)(&Af[4352 + base])   = make_float4(acc[2].x+acc[6].x, acc[2].y+acc[6].y, acc[2].z+acc[6].z, acc[2].w+acc[6].w);
        *(float4*)(&Af[4352 + base+4]) = make_float4(acc[3].x+acc[7].x, acc[3].y+acc[7].y, acc[3].z+acc[7].z, acc[3].w+acc[7].w);
        *(float4*)(&Af[6528 + base])   = make_float4(acc[2].x-acc[6].x, acc[2].y-acc[6].y, acc[2].z-acc[6].z, acc[2].w-acc[6].w);
        *(float4*)(&Af[6528 + base+4]) = make_float4(acc[3].x-acc[7].x, acc[3].y-acc[7].y, acc[3].z-acc[7].z, acc[3].w-acc[7].w);
    }
    __syncthreads();
    // ---- kB compute part (twiddles via rotation recurrence) ----
    {
        int k = t & 31, kxg = t >> 5;
        int kx0 = kxg * 4;
        int sig = k & 1;
        const float* pe = Af + sig * 2176;
        const float* po = Af + 4352 + sig * 2176;
        int a2 = (2 * k) & 127;
        float ca = tabs[a2], sa = tabs[129 + a2];
        float ce = 1.f, se = 0.f;
        float co_ = tabs[k], so_ = tabs[129 + k];
        float4 P1 = {0,0,0,0}, P2 = {0,0,0,0}, P3 = {0,0,0,0}, P4 = {0,0,0,0};
        for (int m = 0; m < 32; ++m) {
            float4 ae01 = *(const float4*)(pe + m * 68 + 2 * kx0);
            float4 ae23 = *(const float4*)(pe + m * 68 + 2 * kx0 + 4);
            float4 ao01 = *(const float4*)(po + m * 68 + 2 * kx0);
            float4 ao23 = *(const float4*)(po + m * 68 + 2 * kx0 + 4);
            P1.x = fmaf(ae01.x, ce, P1.x); P1.x = fmaf(ao01.x, co_, P1.x);
            P2.x = fmaf(ae01.y, se, P2.x); P2.x = fmaf(ao01.y, so_, P2.x);
            P3.x = fmaf(ae01.y, ce, P3.x); P3.x = fmaf(ao01.y, co_, P3.x);
            P4.x = fmaf(ae01.x, se, P4.x); P4.x = fmaf(ao01.x, so_, P4.x);
            P1.y = fmaf(ae01.z, ce, P1.y); P1.y = fmaf(ao01.z, co_, P1.y);
            P2.y = fmaf(ae01.w, se, P2.y); P2.y = fmaf(ao01.w, so_, P2.y);
            P3.y = fmaf(ae01.w, ce, P3.y); P3.y = fmaf(ao01.w, co_, P3.y);
            P4.y = fmaf(ae01.z, se, P4.y); P4.y = fmaf(ao01.z, so_, P4.y);
            P1.z = fmaf(ae23.x, ce, P1.z); P1.z = fmaf(ao23.x, co_, P1.z);
            P2.z = fmaf(ae23.y, se, P2.z); P2.z = fmaf(ao23.y, so_, P2.z);
            P3.z = fmaf(ae23.y, ce, P3.z); P3.z = fmaf(ao23.y, co_, P3.z);
            P4.z = fmaf(ae23.x, se, P4.z); P4.z = fmaf(ao23.x, so_, P4.z);
            P1.w = fmaf(ae23.z, ce, P1.w); P1.w = fmaf(ao23.z, co_, P1.w);
            P2.w = fmaf(ae23.w, se, P2.w); P2.w = fmaf(ao23.w, so_, P2.w);
            P3.w = fmaf(ae23.w, ce, P3.w); P3.w = fmaf(ao23.w, co_, P3.w);
            P4.w = fmaf(ae23.z, se, P4.w); P4.w = fmaf(ao23.z, so_, P4.w);
            float t1 = se * sa, t2 = ce * sa;
            float cen = fmaf(ce, ca, -t1);
            float sen = fmaf(se, ca, t2);
            ce = cen; se = sen;
            float t3 = so_ * sa, t4 = co_ * sa;
            float con = fmaf(co_, ca, -t3);
            float son = fmaf(so_, ca, t4);
            co_ = con; so_ = son;
        }
        float* xfb = XF + bc * 4096;
        *(float4*)(xfb + (k * 32 + kx0) * 2) =
            make_float4(P1.x + P2.x, P3.x - P4.x, P1.y + P2.y, P3.y - P4.y);
        *(float4*)(xfb + (k * 32 + kx0) * 2 + 4) =
            make_float4(P1.z + P2.z, P3.z - P4.z, P1.w + P2.w, P3.w - P4.w);
        if (k) {
            *(float4*)(xfb + ((64 - k) * 32 + kx0) * 2) =
                make_float4(P1.x - P2.x, P3.x + P4.x, P1.y - P2.y, P3.y + P4.y);
            *(float4*)(xfb + ((64 - k) * 32 + kx0) * 2 + 4) =
                make_float4(P1.z - P2.z, P3.z + P4.z, P1.w - P2.w, P3.w + P4.w);
        }
        if (t < 32) {
            int kx = t;
            float re = 0.f, im = 0.f;
            #pragma unroll 8
            for (int m = 0; m < 32; ++m) {
                float2 aep = *(const float2*)(&Af[       m * 68 + 2 * kx]);
                float2 aop = *(const float2*)(&Af[4352 + m * 68 + 2 * kx]);
                float sg = (m & 1) ? -1.f : 1.f;
                re = fmaf(sg, aep.x - aop.y, re);
                im = fmaf(sg, aep.y + aop.x, im);
            }
            xfb[(32 * 32 + kx) * 2]     = re;
            xfb[(32 * 32 + kx) * 2 + 1] = im;
        }
    }
}

// ---- kC v6: async double-buffered staging via global_load_lds -------------
// bid = c<<10 | my<<5 | cot<<2 | mxh<<1 | cih (2048 blocks). Per chunk cc:
// issue stage(cc+1) into buf^1 (async DMA, 6 insts/wave), compute cc from buf,
// ONE barrier. LDS: X 2x16KB + W 2x8KB = 48 KB.
__global__ __launch_bounds__(256) void kC(const float* __restrict__ XF,
                                          const float* __restrict__ Wgt,
                                          float* __restrict__ YF0,
                                          float* __restrict__ YF1) {
    __shared__ __align__(16) float2 Xb[2][2048];  // [buf][ci_l 8][b 16][mx 16]
    __shared__ __align__(16) float  Wb[2][2048];  // [buf][plane 2][ci 8][co 8][mx 16]
    int t = threadIdx.x;
    int lane = t & 63, wid = t >> 6;
    int bid = blockIdx.x;
    int cih = bid & 1;
    int mxh = (bid >> 1) & 1;
    int cot = (bid >> 2) & 7;
    int my  = (bid >> 5) & 31;
    int c   = bid >> 10;
    int co0 = cot * 8;
    int slotbase = (c * 32 + my) * 32 + mxh * 16;
    int mx   = t & 15;
    int co_l = (t >> 4) & 7;
    int bh   = t >> 7;
    int co = co0 + co_l;
    int ci0 = cih * 32;
    float2 acc[8];
    #pragma unroll
    for (int i = 0; i < 8; ++i) acc[i] = make_float2(0.f, 0.f);
    const float* wbase = Wgt + (size_t)c * 4194304 + (size_t)my * 32 + mxh * 16;
    auto stage = [&](int cc, int buf) {
        // X chunk: 16 KB = 16 insts x 1 KB; wave wid issues insts [4w,4w+4)
        #pragma unroll
        for (int i = 0; i < 4; ++i) {
            int inst = wid * 4 + i;
            int u = inst * 64 + lane;              // 16B slot: [ci_l 8][b 16][mxp 8]
            int mxp = u & 7, b = (u >> 3) & 15, ci_l = u >> 7;
            int ci = ci0 + cc * 8 + ci_l;
            const float* g = XF + ((size_t)(b * 64 + ci) * 2048 + slotbase + mxp * 2) * 2;
            float* l = (float*)Xb[buf] + inst * 256;
            __builtin_amdgcn_global_load_lds(g, l, 16, 0, 0);
        }
        // W chunk: 8 KB = 8 insts x 1 KB; wave wid issues insts [2w,2w+2)
        #pragma unroll
        for (int i = 0; i < 2; ++i) {
            int inst = wid * 2 + i;
            int u = inst * 64 + lane;              // 16B slot: [pl 2][ci 8][co 8][mx4 4]
            int mx4 = u & 3, col = (u >> 2) & 7, ci_l = (u >> 5) & 7, pl = u >> 8;
            const float* g = wbase + (size_t)pl * 8388608
                           + ((size_t)(ci0 + cc * 8 + ci_l) * 64 + co0 + col) * 1024
                           + mx4 * 4;
            float* l = Wb[buf] + inst * 256;
            __builtin_amdgcn_global_load_lds(g, l, 16, 0, 0);
        }
    };
#define KC_COMPUTE(BUF)                                                      \
    {                                                                        \
        _Pragma("unroll")                                                    \
        for (int j = 0; j < 8; ++j) {                                        \
            float wre = Wb[BUF][(j * 8 + co_l) * 16 + mx];                   \
            float wim = Wb[BUF][1024 + (j * 8 + co_l) * 16 + mx];            \
            _Pragma("unroll")                                                \
            for (int bb = 0; bb < 8; ++bb) {                                 \
                float2 xv = Xb[BUF][(j * 16 + bh * 8 + bb) * 16 + mx];       \
                acc[bb].x = fmaf(xv.x, wre, acc[bb].x);                      \
                acc[bb].x = fmaf(-xv.y, wim, acc[bb].x);                     \
                acc[bb].y = fmaf(xv.x, wim, acc[bb].y);                      \
                acc[bb].y = fmaf(xv.y, wre, acc[bb].y);                      \
            }                                                                \
        }                                                                    \
    }
    stage(0, 0);
    __syncthreads();          // stage(0) landed
    stage(1, 1);
    KC_COMPUTE(0);
    __syncthreads();          // stage(1) landed, compute(0) done
    stage(2, 0);
    KC_COMPUTE(1);
    __syncthreads();
    stage(3, 1);
    KC_COMPUTE(0);
    __syncthreads();
    KC_COMPUTE(1);
#undef KC_COMPUTE
    float* YF = cih ? YF1 : YF0;
    #pragma unroll
    for (int bb = 0; bb < 8; ++bb) {
        int b = bh * 8 + bb;
        *(float2*)(YF + ((size_t)(b * 64 + co) * 2048 + slotbase + mx) * 2) = acc[bb];
    }
}

// ---- kDE: fused inv H-DFT (folded) + inv W-rDFT (w-folded) + bias ---------
__global__ __launch_bounds__(256) void kDE(const float* __restrict__ YF0,
                                           const float* __restrict__ YF1,
                                           const float* __restrict__ bias,
                                           float* __restrict__ out) {
    __shared__ float tabs[258];
    __shared__ __align__(16) float Ts[4096];  // [q 64][w 64], 16 KB
    __shared__ __align__(16) float U[8448];   // Q[0,2112)+R[2112,4224) -> Zt[64][132]
    build_tab(tabs);
    __syncthreads();
    int t = threadIdx.x;
    size_t bo = blockIdx.x;
    const float inv = 6.103515625e-05f;  // 1/16384
    #pragma unroll
    for (int i = 0; i < 16; ++i) {
        int e = t + i * 256;
        int q = e >> 6, w = e & 63;
        int k = q >> 1;
        int idx = (k * w) & 127;
        float val;
        if (q == 0)      val = inv;
        else if (q == 1) val = 0.f;
        else if (q & 1)  val = -2.f * inv * tabs[129 + idx];
        else             val =  2.f * inv * tabs[idx];
        Ts[e] = val;
    }
    float* Qs = U;
    float* Rs = U + 2112;
    const float* y0 = YF0 + bo * 4096;
    const float* y1 = YF1 + bo * 4096;
    for (int u = t; u < 528; u += 256) {
        int k = u >> 4, kxf = (u & 15) * 4;
        float4 a0 = *(const float4*)(y0 + k * 64 + kxf);
        float4 a1 = *(const float4*)(y1 + k * 64 + kxf);
        float4 a = make_float4(a0.x+a1.x, a0.y+a1.y, a0.z+a1.z, a0.w+a1.w);
        float4 Q, R;
        if (k == 0) { Q = a; R = make_float4(0.f, 0.f, 0.f, 0.f); }
        else if (k == 32) { Q = a; R = make_float4(-a.x, -a.y, -a.z, -a.w); }
        else {
            float4 b0 = *(const float4*)(y0 + (64 - k) * 64 + kxf);
            float4 b1 = *(const float4*)(y1 + (64 - k) * 64 + kxf);
            float4 bb = make_float4(b0.x+b1.x, b0.y+b1.y, b0.z+b1.z, b0.w+b1.w);
            Q = make_float4(a.x+bb.x, a.y+bb.y, a.z+bb.z, a.w+bb.w);
            R = make_float4(a.x-bb.x, a.y-bb.y, a.z-bb.z, a.w-bb.w);
        }
        *(float4*)(&Qs[k * 64 + kxf]) = Q;
        *(float4*)(&Rs[k * 64 + kxf]) = R;
    }
    __syncthreads();
    int hh = t >> 2;
    int kx0 = (t & 3) * 8;
    float4 Ee0 = {0,0,0,0}, Ee1 = {0,0,0,0}, Ee2 = {0,0,0,0}, Ee3 = {0,0,0,0};
    float4 Eo0 = {0,0,0,0}, Eo1 = {0,0,0,0}, Eo2 = {0,0,0,0}, Eo3 = {0,0,0,0};
    int idx = 0;
#define KD_BODY(E0, E1, E2, E3, kk)                                          \
    {                                                                        \
        float c = tabs[idx], s = tabs[129 + idx];                            \
        const float4* Qp = (const float4*)(&Qs[(kk) * 64 + kx0 * 2]);        \
        const float4* Rp = (const float4*)(&Rs[(kk) * 64 + kx0 * 2]);        \
        float4 Qv, Rv;                                                       \
        Qv = Qp[0]; Rv = Rp[0];                                              \
        E0.x = fmaf(c, Qv.x, E0.x); E0.x = fmaf(-s, Rv.y, E0.x);             \
        E0.y = fmaf(c, Qv.y, E0.y); E0.y = fmaf(s, Rv.x, E0.y);              \
        E0.z = fmaf(c, Qv.z, E0.z); E0.z = fmaf(-s, Rv.w, E0.z);             \
        E0.w = fmaf(c, Qv.w, E0.w); E0.w = fmaf(s, Rv.z, E0.w);              \
        Qv = Qp[1]; Rv = Rp[1];                                              \
        E1.x = fmaf(c, Qv.x, E1.x); E1.x = fmaf(-s, Rv.y, E1.x);             \
        E1.y = fmaf(c, Qv.y, E1.y); E1.y = fmaf(s, Rv.x, E1.y);              \
        E1.z = fmaf(c, Qv.z, E1.z); E1.z = fmaf(-s, Rv.w, E1.z);             \
        E1.w = fmaf(c, Qv.w, E1.w); E1.w = fmaf(s, Rv.z, E1.w);              \
        Qv = Qp[2]; Rv = Rp[2];                                              \
        E2.x = fmaf(c, Qv.x, E2.x); E2.x = fmaf(-s, Rv.y, E2.x);             \
        E2.y = fmaf(c, Qv.y, E2.y); E2.y = fmaf(s, Rv.x, E2.y);              \
        E2.z = fmaf(c, Qv.z, E2.z); E2.z = fmaf(-s, Rv.w, E2.z);             \
        E2.w = fmaf(c, Qv.w, E2.w); E2.w = fmaf(s, Rv.z, E2.w);              \
        Qv = Qp[3]; Rv = Rp[3];                                              \
        E3.x = fmaf(c, Qv.x, E3.x); E3.x = fmaf(-s, Rv.y, E3.x);             \
        E3.y = fmaf(c, Qv.y, E3.y); E3.y = fmaf(s, Rv.x, E3.y);              \
        E3.z = fmaf(c, Qv.z, E3.z); E3.z = fmaf(-s, Rv.w, E3.z);             \
        E3.w = fmaf(c, Qv.w, E3.w); E3.w = fmaf(s, Rv.z, E3.w);              \
        idx = (idx + hh) & 127;                                              \
    }
    for (int u = 0; u < 16; ++u) {
        KD_BODY(Ee0, Ee1, Ee2, Ee3, 2 * u);
        KD_BODY(Eo0, Eo1, Eo2, Eo3, 2 * u + 1);
    }
    KD_BODY(Ee0, Ee1, Ee2, Ee3, 32);
#undef KD_BODY
    __syncthreads();  // all Q/R reads done -> reuse U as Zt
    float* Zt = U;    // [q][h], stride 132
    {
        float* zr = &Zt[(2 * kx0) * 132 + hh];        // row hh
        float* zs = zr + 64;                          // row hh+64
        zr[0*132]  = Ee0.x + Eo0.x;  zs[0*132]  = Ee0.x - Eo0.x;
        zr[1*132]  = Ee0.y + Eo0.y;  zs[1*132]  = Ee0.y - Eo0.y;
        zr[2*132]  = Ee0.z + Eo0.z;  zs[2*132]  = Ee0.z - Eo0.z;
        zr[3*132]  = Ee0.w + Eo0.w;  zs[3*132]  = Ee0.w - Eo0.w;
        zr[4*132]  = Ee1.x + Eo1.x;  zs[4*132]  = Ee1.x - Eo1.x;
        zr[5*132]  = Ee1.y + Eo1.y;  zs[5*132]  = Ee1.y - Eo1.y;
        zr[6*132]  = Ee1.z + Eo1.z;  zs[6*132]  = Ee1.z - Eo1.z;
        zr[7*132]  = Ee1.w + Eo1.w;  zs[7*132]  = Ee1.w - Eo1.w;
        zr[8*132]  = Ee2.x + Eo2.x;  zs[8*132]  = Ee2.x - Eo2.x;
        zr[9*132]  = Ee2.y + Eo2.y;  zs[9*132]  = Ee2.y - Eo2.y;
        zr[10*132] = Ee2.z + Eo2.z;  zs[10*132] = Ee2.z - Eo2.z;
        zr[11*132] = Ee2.w + Eo2.w;  zs[11*132] = Ee2.w - Eo2.w;
        zr[12*132] = Ee3.x + Eo3.x;  zs[12*132] = Ee3.x - Eo3.x;
        zr[13*132] = Ee3.y + Eo3.y;  zs[13*132] = Ee3.y - Eo3.y;
        zr[14*132] = Ee3.z + Eo3.z;  zs[14*132] = Ee3.z - Eo3.z;
        zr[15*132] = Ee3.w + Eo3.w;  zs[15*132] = Ee3.w - Eo3.w;
    }
    __syncthreads();
    // kE GEMM with w-fold: thread (w0 = (t&31)*2, h0 = (t>>5)*16).
    int w0 = (t & 31) * 2;
    int h0 = (t >> 5) * 16;
    float2 We[16], Wo[16];
    #pragma unroll
    for (int j = 0; j < 16; ++j) { We[j] = make_float2(0.f, 0.f); Wo[j] = make_float2(0.f, 0.f); }
#define KE_K(E, K)                                                            \
    {                                                                         \
        const float4* zpe = (const float4*)(&Zt[(2*(K)) * 132 + h0]);         \
        const float4* zpo = (const float4*)(&Zt[(2*(K)+1) * 132 + h0]);       \
        float2 twe = *(const float2*)(&Ts[(2*(K)) * 64 + w0]);                \
        float2 two = *(const float2*)(&Ts[(2*(K)+1) * 64 + w0]);              \
        float4 e0 = zpe[0], e1 = zpe[1], e2 = zpe[2], e3 = zpe[3];            \
        float4 o0 = zpo[0], o1 = zpo[1], o2 = zpo[2], o3 = zpo[3];            \
        E[0].x  = fmaf(e0.x, twe.x, E[0].x);  E[0].x  = fmaf(o0.x, two.x, E[0].x);   \
        E[0].y  = fmaf(e0.x, twe.y, E[0].y);  E[0].y  = fmaf(o0.x, two.y, E[0].y);   \
        E[1].x  = fmaf(e0.y, twe.x, E[1].x);  E[1].x  = fmaf(o0.y, two.x, E[1].x);   \
        E[1].y  = fmaf(e0.y, twe.y, E[1].y);  E[1].y  = fmaf(o0.y, two.y, E[1].y);   \
        E[2].x  = fmaf(e0.z, twe.x, E[2].x);  E[2].x  = fmaf(o0.z, two.x, E[2].x);   \
        E[2].y  = fmaf(e0.z, twe.y, E[2].y);  E[2].y  = fmaf(o0.z, two.y, E[2].y);   \
        E[3].x  = fmaf(e0.w, twe.x, E[3].x);  E[3].x  = fmaf(o0.w, two.x, E[3].x);   \
        E[3].y  = fmaf(e0.w, twe.y, E[3].y);  E[3].y  = fmaf(o0.w, two.y, E[3].y);   \
        E[4].x  = fmaf(e1.x, twe.x, E[4].x);  E[4].x  = fmaf(o1.x, two.x, E[4].x);   \
        E[4].y  = fmaf(e1.x, twe.y, E[4].y);  E[4].y  = fmaf(o1.x, two.y, E[4].y);   \
        E[5].x  = fmaf(e1.y, twe.x, E[5].x);  E[5].x  = fmaf(o1.y, two.x, E[5].x);   \
        E[5].y  = fmaf(e1.y, twe.y, E[5].y);  E[5].y  = fmaf(o1.y, two.y, E[5].y);   \
        E[6].x  = fmaf(e1.z, twe.x, E[6].x);  E[6].x  = fmaf(o1.z, two.x, E[6].x);   \
        E[6].y  = fmaf(e1.z, twe.y, E[6].y);  E[6].y  = fmaf(o1.z, two.y, E[6].y);   \
        E[7].x  = fmaf(e1.w, twe.x, E[7].x);  E[7].x  = fmaf(o1.w, two.x, E[7].x);   \
        E[7].y  = fmaf(e1.w, twe.y, E[7].y);  E[7].y  = fmaf(o1.w, two.y, E[7].y);   \
        E[8].x  = fmaf(e2.x, twe.x, E[8].x);  E[8].x  = fmaf(o2.x, two.x, E[8].x);   \
        E[8].y  = fmaf(e2.x, twe.y, E[8].y);  E[8].y  = fmaf(o2.x, two.y, E[8].y);   \
        E[9].x  = fmaf(e2.y, twe.x, E[9].x);  E[9].x  = fmaf(o2.y, two.x, E[9].x);   \
        E[9].y  = fmaf(e2.y, twe.y, E[9].y);  E[9].y  = fmaf(o2.y, two.y, E[9].y);   \
        E[10].x = fmaf(e2.z, twe.x, E[10].x); E[10].x = fmaf(o2.z, two.x, E[10].x);  \
        E[10].y = fmaf(e2.z, twe.y, E[10].y); E[10].y = fmaf(o2.z, two.y, E[10].y);  \
        E[11].x = fmaf(e2.w, twe.x, E[11].x); E[11].x = fmaf(o2.w, two.x, E[11].x);  \
        E[11].y = fmaf(e2.w, twe.y, E[11].y); E[11].y = fmaf(o2.w, two.y, E[11].y);  \
        E[12].x = fmaf(e3.x, twe.x, E[12].x); E[12].x = fmaf(o3.x, two.x, E[12].x);  \
        E[12].y = fmaf(e3.x, twe.y, E[12].y); E[12].y = fmaf(o3.x, two.y, E[12].y);  \
        E[13].x = fmaf(e3.y, twe.x, E[13].x); E[13].x = fmaf(o3.y, two.x, E[13].x);  \
        E[13].y = fmaf(e3.y, twe.y, E[13].y); E[13].y = fmaf(o3.y, two.y, E[13].y);  \
        E[14].x = fmaf(e3.z, twe.x, E[14].x); E[14].x = fmaf(o3.z, two.x, E[14].x);  \
        E[14].y = fmaf(e3.z, twe.y, E[14].y); E[14].y = fmaf(o3.z, two.y, E[14].y);  \
        E[15].x = fmaf(e3.w, twe.x, E[15].x); E[15].x = fmaf(o3.w, two.x, E[15].x);  \
        E[15].y = fmaf(e3.w, twe.y, E[15].y); E[15].y = fmaf(o3.w, two.y, E[15].y);  \
    }
    #pragma unroll 2
    for (int u = 0; u < 16; ++u) {
        KE_K(We, 2 * u);       // k even
        KE_K(Wo, 2 * u + 1);   // k odd
    }
#undef KE_K
    float bv = bias[(int)(bo & 63)];
    float* ob = out + ((size_t)(bo * 128 + h0)) * 128;
    #pragma unroll
    for (int j = 0; j < 16; ++j) {
        float2 lo = make_float2(We[j].x + Wo[j].x + bv, We[j].y + Wo[j].y + bv);
        float2 hi = make_float2(We[j].x - Wo[j].x + bv, We[j].y - Wo[j].y + bv);
        *(float2*)(ob + (size_t)j * 128 + w0)      = lo;
        *(float2*)(ob + (size_t)j * 128 + w0 + 64) = hi;
    }
}

extern "C" void kernel_launch(void* const* d_in, const int* in_sizes, int n_in,
                              void* d_out, int out_size, void* d_ws, size_t ws_size,
                              hipStream_t stream) {
    (void)in_sizes; (void)n_in; (void)out_size; (void)ws_size;
    const float* x    = (const float*)d_in[0];
    const float* wgt  = (const float*)d_in[1];
    const float* bias = (const float*)d_in[2];
    float* outp   = (float*)d_out;
    char* ws = (char*)d_ws;
    float* bufXF  = (float*)(ws + (48u << 20));     // [48, 64 MiB)
    float* bufYF0 = (float*)(ws);                   // [0, 16 MiB)
    float* bufYF1 = (float*)(ws + (16u << 20));     // [16, 32 MiB)
    hipLaunchKernelGGL(kAB, dim3(1024), dim3(256), 0, stream, x, bufXF);
    hipLaunchKernelGGL(kC, dim3(2048), dim3(256), 0, stream, bufXF, wgt, bufYF0, bufYF1);
    hipLaunchKernelGGL(kDE, dim3(1024), dim3(256), 0, stream, bufYF0, bufYF1, bias, outp);
}

// Round 17
// 114.094 us; speedup vs baseline: 1.0296x; 1.0296x over previous
//
#include <hip/hip_runtime.h>

// FactorizedSpectralConv2d: B=16, CIN=COUT=64, H=W=128, MH=MW=32, super_res=1
// kAB (W-rDFT GEMM + folded H-DFT) -> kC (channel mix, full-line W streaming,
// async dbuf) -> kDE (inv H-DFT folded + inv W-rDFT w-folded + bias).
// ws layout (64 MiB): XF[48,64) ; YF0[0,16) ; YF1[16,32)

__device__ __forceinline__ void build_tab(float* tabs) {
    int t = threadIdx.x;
    if (t < 128) {
        float ang = (float)t * 0.049087385212340517f;  // 2*pi/128
        float s, c;
        sincosf(ang, &s, &c);
        tabs[t] = c;        // cos at [0..127]
        tabs[129 + t] = s;  // sin at [129..256]
    }
}

// ---- kAB: fused W-rDFT (per (b,ci) image) + folded H-DFT ------------------
__global__ __launch_bounds__(256) void kAB(const float* __restrict__ x,
                                           float* __restrict__ XF) {
    __shared__ float tabs[258];
    __shared__ __align__(16) float smem[8704];  // Twid[0,4096)|xeo[4096,8256); later Af[0,8704)
    build_tab(tabs);
    __syncthreads();
    int t = threadIdx.x;
    size_t bc = blockIdx.x;  // b*64+ci, 1024 blocks
    float* Twid = smem;
    float* xeo  = smem + 4096;
    #pragma unroll
    for (int i = 0; i < 16; ++i) {
        int e = t + i * 256;
        int w = e >> 6, q = e & 63, kx = q >> 1;
        int idx = (w * kx) & 127;
        Twid[e] = (q & 1) ? -tabs[129 + idx] : tabs[idx];
    }
    const float* xb = x + bc * 16384;
    int th = t & 31;   // h in {2th, 2th+1, 2th+64, 2th+65}
    int tq = t >> 5;   // q in [8tq, 8tq+8)
    int q0 = tq * 8;
    int wl4 = (t & 3) * 4;  // staging lanes
    int hb  = t >> 2;
    float4 rlo0, rhi0, rlo1, rhi1;
    auto loadR = [&](int ph) {
        rlo0 = *(const float4*)(xb + hb * 128 + ph * 16 + wl4);
        rhi0 = *(const float4*)(xb + hb * 128 + ph * 16 + wl4 + 64);
        rlo1 = *(const float4*)(xb + (64 + hb) * 128 + ph * 16 + wl4);
        rhi1 = *(const float4*)(xb + (64 + hb) * 128 + ph * 16 + wl4 + 64);
    };
    auto writeR = [&]() {
        int h0 = hb, h1 = 64 + hb;
        *(float2*)(&xeo[(wl4+0)*260 + 2*h0]) = make_float2(rlo0.x+rhi0.x, rlo0.x-rhi0.x);
        *(float2*)(&xeo[(wl4+1)*260 + 2*h0]) = make_float2(rlo0.y+rhi0.y, rlo0.y-rhi0.y);
        *(float2*)(&xeo[(wl4+2)*260 + 2*h0]) = make_float2(rlo0.z+rhi0.z, rlo0.z-rhi0.z);
        *(float2*)(&xeo[(wl4+3)*260 + 2*h0]) = make_float2(rlo0.w+rhi0.w, rlo0.w-rhi0.w);
        *(float2*)(&xeo[(wl4+0)*260 + 2*h1]) = make_float2(rlo1.x+rhi1.x, rlo1.x-rhi1.x);
        *(float2*)(&xeo[(wl4+1)*260 + 2*h1]) = make_float2(rlo1.y+rhi1.y, rlo1.y-rhi1.y);
        *(float2*)(&xeo[(wl4+2)*260 + 2*h1]) = make_float2(rlo1.z+rhi1.z, rlo1.z-rhi1.z);
        *(float2*)(&xeo[(wl4+3)*260 + 2*h1]) = make_float2(rlo1.w+rhi1.w, rlo1.w-rhi1.w);
    };
    loadR(0);
    writeR();
    float4 acc[8];
    #pragma unroll
    for (int j = 0; j < 8; ++j) acc[j] = make_float4(0.f, 0.f, 0.f, 0.f);
    __syncthreads();  // xeo(0) ready
    for (int ph = 0; ph < 4; ++ph) {
        if (ph < 3) loadR(ph + 1);  // loads fly under compute
        #pragma unroll 4
        for (int wl = 0; wl < 16; ++wl) {
            int w = ph * 16 + wl;
            const float* xr = &xeo[wl * 260 + 4 * th];
            float4 d0  = *(const float4*)(xr);         // ve,vo for h=2th, 2th+1
            float4 d1  = *(const float4*)(xr + 128);   // ve,vo for h+64
            float4 tw0 = *(const float4*)(&Twid[w * 64 + q0]);
            float4 tw1 = *(const float4*)(&Twid[w * 64 + q0 + 4]);
            acc[0].x = fmaf(d0.x, tw0.x, acc[0].x); acc[0].y = fmaf(d0.x, tw0.y, acc[0].y);
            acc[0].z = fmaf(d0.y, tw0.z, acc[0].z); acc[0].w = fmaf(d0.y, tw0.w, acc[0].w);
            acc[1].x = fmaf(d0.x, tw1.x, acc[1].x); acc[1].y = fmaf(d0.x, tw1.y, acc[1].y);
            acc[1].z = fmaf(d0.y, tw1.z, acc[1].z); acc[1].w = fmaf(d0.y, tw1.w, acc[1].w);
            acc[2].x = fmaf(d0.z, tw0.x, acc[2].x); acc[2].y = fmaf(d0.z, tw0.y, acc[2].y);
            acc[2].z = fmaf(d0.w, tw0.z, acc[2].z); acc[2].w = fmaf(d0.w, tw0.w, acc[2].w);
            acc[3].x = fmaf(d0.z, tw1.x, acc[3].x); acc[3].y = fmaf(d0.z, tw1.y, acc[3].y);
            acc[3].z = fmaf(d0.w, tw1.z, acc[3].z); acc[3].w = fmaf(d0.w, tw1.w, acc[3].w);
            acc[4].x = fmaf(d1.x, tw0.x, acc[4].x); acc[4].y = fmaf(d1.x, tw0.y, acc[4].y);
            acc[4].z = fmaf(d1.y, tw0.z, acc[4].z); acc[4].w = fmaf(d1.y, tw0.w, acc[4].w);
            acc[5].x = fmaf(d1.x, tw1.x, acc[5].x); acc[5].y = fmaf(d1.x, tw1.y, acc[5].y);
            acc[5].z = fmaf(d1.y, tw1.z, acc[5].z); acc[5].w = fmaf(d1.y, tw1.w, acc[5].w);
            acc[6].x = fmaf(d1.z, tw0.x, acc[6].x); acc[6].y = fmaf(d1.z, tw0.y, acc[6].y);
            acc[6].z = fmaf(d1.w, tw0.z, acc[6].z); acc[6].w = fmaf(d1.w, tw0.w, acc[6].w);
            acc[7].x = fmaf(d1.z, tw1.x, acc[7].x); acc[7].y = fmaf(d1.z, tw1.y, acc[7].y);
            acc[7].z = fmaf(d1.w, tw1.z, acc[7].z); acc[7].w = fmaf(d1.w, tw1.w, acc[7].w);
        }
        __syncthreads();
        if (ph < 3) {
            writeR();
            __syncthreads();
        }
    }
    // In-register (h, h+64) fold -> Af planes, row stride 68.
    float* Af = smem;
    {
        int base = th * 68 + q0;
        *(float4*)(&Af[base])          = make_float4(acc[0].x+acc[4].x, acc[0].y+acc[4].y, acc[0].z+acc[4].z, acc[0].w+acc[4].w);
        *(float4*)(&Af[base + 4])      = make_float4(acc[1].x+acc[5].x, acc[1].y+acc[5].y, acc[1].z+acc[5].z, acc[1].w+acc[5].w);
        *(float4*)(&Af[2176 + base])   = make_float4(acc[0].x-acc[4].x, acc[0].y-acc[4].y, acc[0].z-acc[4].z, acc[0].w-acc[4].w);
        *(float4*)(&Af[2176 + base+4]) = make_float4(acc[1].x-acc[5].x, acc[1].y-acc[5].y, acc[1].z-acc[5].z, acc[1].w-acc[5].w);
        *(float4*)(&Af[4352 + base])   = make_float4(acc[2].x+acc[6].x, acc[2].y+acc[6].y, acc[2].z+acc[6].z, acc[2].w+acc[6].w);
        *(float4*)(&Af[4352 + base+4]) = make_float4(acc[3].x+acc[7].x, acc[3].y+acc[7].y, acc[3].z+acc[7].z, acc[3].w+acc[7].w);
        *(float4*)(&Af[6528 + base])   = make_float4(acc[2].x-acc[6].x, acc[2].y-acc[6].y, acc[2].z-acc[6].z, acc[2].w-acc[6].w);
        *(float4*)(&Af[6528 + base+4]) = make_float4(acc[3].x-acc[7].x, acc[3].y-acc[7].y, acc[3].z-acc[7].z, acc[3].w-acc[7].w);
    }
    __syncthreads();
    // ---- kB compute part (twiddles via rotation recurrence) ----
    {
        int k = t & 31, kxg = t >> 5;
        int kx0 = kxg * 4;
        int sig = k & 1;
        const float* pe = Af + sig * 2176;
        const float* po = Af + 4352 + sig * 2176;
        int a2 = (2 * k) & 127;
        float ca = tabs[a2], sa = tabs[129 + a2];
        float ce = 1.f, se = 0.f;
        float co_ = tabs[k], so_ = tabs[129 + k];
        float4 P1 = {0,0,0,0}, P2 = {0,0,0,0}, P3 = {0,0,0,0}, P4 = {0,0,0,0};
        for (int m = 0; m < 32; ++m) {
            float4 ae01 = *(const float4*)(pe + m * 68 + 2 * kx0);
            float4 ae23 = *(const float4*)(pe + m * 68 + 2 * kx0 + 4);
            float4 ao01 = *(const float4*)(po + m * 68 + 2 * kx0);
            float4 ao23 = *(const float4*)(po + m * 68 + 2 * kx0 + 4);
            P1.x = fmaf(ae01.x, ce, P1.x); P1.x = fmaf(ao01.x, co_, P1.x);
            P2.x = fmaf(ae01.y, se, P2.x); P2.x = fmaf(ao01.y, so_, P2.x);
            P3.x = fmaf(ae01.y, ce, P3.x); P3.x = fmaf(ao01.y, co_, P3.x);
            P4.x = fmaf(ae01.x, se, P4.x); P4.x = fmaf(ao01.x, so_, P4.x);
            P1.y = fmaf(ae01.z, ce, P1.y); P1.y = fmaf(ao01.z, co_, P1.y);
            P2.y = fmaf(ae01.w, se, P2.y); P2.y = fmaf(ao01.w, so_, P2.y);
            P3.y = fmaf(ae01.w, ce, P3.y); P3.y = fmaf(ao01.w, co_, P3.y);
            P4.y = fmaf(ae01.z, se, P4.y); P4.y = fmaf(ao01.z, so_, P4.y);
            P1.z = fmaf(ae23.x, ce, P1.z); P1.z = fmaf(ao23.x, co_, P1.z);
            P2.z = fmaf(ae23.y, se, P2.z); P2.z = fmaf(ao23.y, so_, P2.z);
            P3.z = fmaf(ae23.y, ce, P3.z); P3.z = fmaf(ao23.y, co_, P3.z);
            P4.z = fmaf(ae23.x, se, P4.z); P4.z = fmaf(ao23.x, so_, P4.z);
            P1.w = fmaf(ae23.z, ce, P1.w); P1.w = fmaf(ao23.z, co_, P1.w);
            P2.w = fmaf(ae23.w, se, P2.w); P2.w = fmaf(ao23.w, so_, P2.w);
            P3.w = fmaf(ae23.w, ce, P3.w); P3.w = fmaf(ao23.w, co_, P3.w);
            P4.w = fmaf(ae23.z, se, P4.w); P4.w = fmaf(ao23.z, so_, P4.w);
            float t1 = se * sa, t2 = ce * sa;
            float cen = fmaf(ce, ca, -t1);
            float sen = fmaf(se, ca, t2);
            ce = cen; se = sen;
            float t3 = so_ * sa, t4 = co_ * sa;
            float con = fmaf(co_, ca, -t3);
            float son = fmaf(so_, ca, t4);
            co_ = con; so_ = son;
        }
        float* xfb = XF + bc * 4096;
        *(float4*)(xfb + (k * 32 + kx0) * 2) =
            make_float4(P1.x + P2.x, P3.x - P4.x, P1.y + P2.y, P3.y - P4.y);
        *(float4*)(xfb + (k * 32 + kx0) * 2 + 4) =
            make_float4(P1.z + P2.z, P3.z - P4.z, P1.w + P2.w, P3.w - P4.w);
        if (k) {
            *(float4*)(xfb + ((64 - k) * 32 + kx0) * 2) =
                make_float4(P1.x - P2.x, P3.x + P4.x, P1.y - P2.y, P3.y + P4.y);
            *(float4*)(xfb + ((64 - k) * 32 + kx0) * 2 + 4) =
                make_float4(P1.z - P2.z, P3.z + P4.z, P1.w - P2.w, P3.w + P4.w);
        }
        if (t < 32) {
            int kx = t;
            float re = 0.f, im = 0.f;
            #pragma unroll 8
            for (int m = 0; m < 32; ++m) {
                float2 aep = *(const float2*)(&Af[       m * 68 + 2 * kx]);
                float2 aop = *(const float2*)(&Af[4352 + m * 68 + 2 * kx]);
                float sg = (m & 1) ? -1.f : 1.f;
                re = fmaf(sg, aep.x - aop.y, re);
                im = fmaf(sg, aep.y + aop.x, im);
            }
            xfb[(32 * 32 + kx) * 2]     = re;
            xfb[(32 * 32 + kx) * 2 + 1] = im;
        }
    }
}

// ---- kC v7: full-line W streaming (no mxh split), async dbuf --------------
// bid = c<<9 | my<<4 | cot<<1 | cih (1024 blocks). Thread=(co_l 8, mx 32),
// acc over all 16 b. ci chunked by 4 (8 chunks). Each W 128B line read once
// by exactly one block, fully contiguous per (pl,ci,co).
// LDS: X 2x16KB + W 2x8KB = 48 KB -> 3 blocks/CU.
__global__ __launch_bounds__(256) void kC(const float* __restrict__ XF,
                                          const float* __restrict__ Wgt,
                                          float* __restrict__ YF0,
                                          float* __restrict__ YF1) {
    __shared__ __align__(16) float Xb[2][4096];  // [buf][ci_l 4][b 16][mx 32] cplx
    __shared__ __align__(16) float Wb[2][2048];  // [buf][pl 2][ci_l 4][co_l 8][mx 32]
    int t = threadIdx.x;
    int lane = t & 63, wid = t >> 6;
    int bid = blockIdx.x;
    int cih = bid & 1;
    int cot = (bid >> 1) & 7;
    int my  = (bid >> 4) & 31;
    int c   = bid >> 9;
    int co0 = cot * 8;
    int slotbase = (c * 32 + my) * 32;  // + mx
    int mx   = t & 31;
    int co_l = t >> 5;
    int co = co0 + co_l;
    int ci0 = cih * 32;
    float2 acc[16];
    #pragma unroll
    for (int i = 0; i < 16; ++i) acc[i] = make_float2(0.f, 0.f);
    const float* wbase = Wgt + (size_t)c * 4194304 + (size_t)my * 32;
    auto stage = [&](int cc, int buf) {
        // X chunk: 16 KB = 16 insts x 1 KB; wave wid issues [4w, 4w+4)
        #pragma unroll
        for (int i = 0; i < 4; ++i) {
            int inst = wid * 4 + i;
            int u = inst * 64 + lane;             // [ci_l 4][b 16][mxp 16]
            int mxp = u & 15, b = (u >> 4) & 15, ci_l = u >> 8;
            int ci = ci0 + cc * 4 + ci_l;
            const float* g = XF + ((size_t)(b * 64 + ci) * 2048 + slotbase + mxp * 2) * 2;
            float* l = Xb[buf] + inst * 256;
            __builtin_amdgcn_global_load_lds(g, l, 16, 0, 0);
        }
        // W chunk: 8 KB = 8 insts x 1 KB; wave wid issues [2w, 2w+2)
        // 8 consecutive lanes = one full 128B (pl,ci,co) row
        #pragma unroll
        for (int i = 0; i < 2; ++i) {
            int inst = wid * 2 + i;
            int u = inst * 64 + lane;             // [pl 2][ci_l 4][co_l 8][mx4 8]
            int mx4 = u & 7, col = (u >> 3) & 7, ci_l = (u >> 6) & 3, pl = u >> 8;
            const float* g = wbase + (size_t)pl * 8388608
                           + ((size_t)(ci0 + cc * 4 + ci_l) * 64 + co0 + col) * 1024
                           + mx4 * 4;
            float* l = Wb[buf] + inst * 256;
            __builtin_amdgcn_global_load_lds(g, l, 16, 0, 0);
        }
    };
#define KC_COMPUTE(BUF)                                                      \
    {                                                                        \
        _Pragma("unroll")                                                    \
        for (int j = 0; j < 4; ++j) {                                        \
            float wre = Wb[BUF][(j * 8 + co_l) * 32 + mx];                   \
            float wim = Wb[BUF][1024 + (j * 8 + co_l) * 32 + mx];            \
            _Pragma("unroll")                                                \
            for (int b = 0; b < 16; ++b) {                                   \
                float2 xv = *(const float2*)(&Xb[BUF][((j * 16 + b) * 32 + mx) * 2]); \
                acc[b].x = fmaf(xv.x, wre, acc[b].x);                        \
                acc[b].x = fmaf(-xv.y, wim, acc[b].x);                       \
                acc[b].y = fmaf(xv.x, wim, acc[b].y);                        \
                acc[b].y = fmaf(xv.y, wre, acc[b].y);                        \
            }                                                                \
        }                                                                    \
    }
    stage(0, 0);
    __syncthreads();
    stage(1, 1); KC_COMPUTE(0); __syncthreads();
    stage(2, 0); KC_COMPUTE(1); __syncthreads();
    stage(3, 1); KC_COMPUTE(0); __syncthreads();
    stage(4, 0); KC_COMPUTE(1); __syncthreads();
    stage(5, 1); KC_COMPUTE(0); __syncthreads();
    stage(6, 0); KC_COMPUTE(1); __syncthreads();
    stage(7, 1); KC_COMPUTE(0); __syncthreads();
    KC_COMPUTE(1);
#undef KC_COMPUTE
    float* YF = cih ? YF1 : YF0;
    #pragma unroll
    for (int b = 0; b < 16; ++b) {
        *(float2*)(YF + ((size_t)(b * 64 + co) * 2048 + slotbase + mx) * 2) = acc[b];
    }
}

// ---- kDE: fused inv H-DFT (folded) + inv W-rDFT (w-folded) + bias ---------
__global__ __launch_bounds__(256) void kDE(const float* __restrict__ YF0,
                                           const float* __restrict__ YF1,
                                           const float* __restrict__ bias,
                                           float* __restrict__ out) {
    __shared__ float tabs[258];
    __shared__ __align__(16) float Ts[4096];  // [q 64][w 64], 16 KB
    __shared__ __align__(16) float U[8448];   // Q[0,2112)+R[2112,4224) -> Zt[64][132]
    build_tab(tabs);
    __syncthreads();
    int t = threadIdx.x;
    size_t bo = blockIdx.x;
    const float inv = 6.103515625e-05f;  // 1/16384
    #pragma unroll
    for (int i = 0; i < 16; ++i) {
        int e = t + i * 256;
        int q = e >> 6, w = e & 63;
        int k = q >> 1;
        int idx = (k * w) & 127;
        float val;
        if (q == 0)      val = inv;
        else if (q == 1) val = 0.f;
        else if (q & 1)  val = -2.f * inv * tabs[129 + idx];
        else             val =  2.f * inv * tabs[idx];
        Ts[e] = val;
    }
    float* Qs = U;
    float* Rs = U + 2112;
    const float* y0 = YF0 + bo * 4096;
    const float* y1 = YF1 + bo * 4096;
    for (int u = t; u < 528; u += 256) {
        int k = u >> 4, kxf = (u & 15) * 4;
        float4 a0 = *(const float4*)(y0 + k * 64 + kxf);
        float4 a1 = *(const float4*)(y1 + k * 64 + kxf);
        float4 a = make_float4(a0.x+a1.x, a0.y+a1.y, a0.z+a1.z, a0.w+a1.w);
        float4 Q, R;
        if (k == 0) { Q = a; R = make_float4(0.f, 0.f, 0.f, 0.f); }
        else if (k == 32) { Q = a; R = make_float4(-a.x, -a.y, -a.z, -a.w); }
        else {
            float4 b0 = *(const float4*)(y0 + (64 - k) * 64 + kxf);
            float4 b1 = *(const float4*)(y1 + (64 - k) * 64 + kxf);
            float4 bb = make_float4(b0.x+b1.x, b0.y+b1.y, b0.z+b1.z, b0.w+b1.w);
            Q = make_float4(a.x+bb.x, a.y+bb.y, a.z+bb.z, a.w+bb.w);
            R = make_float4(a.x-bb.x, a.y-bb.y, a.z-bb.z, a.w-bb.w);
        }
        *(float4*)(&Qs[k * 64 + kxf]) = Q;
        *(float4*)(&Rs[k * 64 + kxf]) = R;
    }
    __syncthreads();
    int hh = t >> 2;
    int kx0 = (t & 3) * 8;
    float4 Ee0 = {0,0,0,0}, Ee1 = {0,0,0,0}, Ee2 = {0,0,0,0}, Ee3 = {0,0,0,0};
    float4 Eo0 = {0,0,0,0}, Eo1 = {0,0,0,0}, Eo2 = {0,0,0,0}, Eo3 = {0,0,0,0};
    int idx = 0;
#define KD_BODY(E0, E1, E2, E3, kk)                                          \
    {                                                                        \
        float c = tabs[idx], s = tabs[129 + idx];                            \
        const float4* Qp = (const float4*)(&Qs[(kk) * 64 + kx0 * 2]);        \
        const float4* Rp = (const float4*)(&Rs[(kk) * 64 + kx0 * 2]);        \
        float4 Qv, Rv;                                                       \
        Qv = Qp[0]; Rv = Rp[0];                                              \
        E0.x = fmaf(c, Qv.x, E0.x); E0.x = fmaf(-s, Rv.y, E0.x);             \
        E0.y = fmaf(c, Qv.y, E0.y); E0.y = fmaf(s, Rv.x, E0.y);              \
        E0.z = fmaf(c, Qv.z, E0.z); E0.z = fmaf(-s, Rv.w, E0.z);             \
        E0.w = fmaf(c, Qv.w, E0.w); E0.w = fmaf(s, Rv.z, E0.w);              \
        Qv = Qp[1]; Rv = Rp[1];                                              \
        E1.x = fmaf(c, Qv.x, E1.x); E1.x = fmaf(-s, Rv.y, E1.x);             \
        E1.y = fmaf(c, Qv.y, E1.y); E1.y = fmaf(s, Rv.x, E1.y);              \
        E1.z = fmaf(c, Qv.z, E1.z); E1.z = fmaf(-s, Rv.w, E1.z);             \
        E1.w = fmaf(c, Qv.w, E1.w); E1.w = fmaf(s, Rv.z, E1.w);              \
        Qv = Qp[2]; Rv = Rp[2];                                              \
        E2.x = fmaf(c, Qv.x, E2.x); E2.x = fmaf(-s, Rv.y, E2.x);             \
        E2.y = fmaf(c, Qv.y, E2.y); E2.y = fmaf(s, Rv.x, E2.y);              \
        E2.z = fmaf(c, Qv.z, E2.z); E2.z = fmaf(-s, Rv.w, E2.z);             \
        E2.w = fmaf(c, Qv.w, E2.w); E2.w = fmaf(s, Rv.z, E2.w);              \
        Qv = Qp[3]; Rv = Rp[3];                                              \
        E3.x = fmaf(c, Qv.x, E3.x); E3.x = fmaf(-s, Rv.y, E3.x);             \
        E3.y = fmaf(c, Qv.y, E3.y); E3.y = fmaf(s, Rv.x, E3.y);              \
        E3.z = fmaf(c, Qv.z, E3.z); E3.z = fmaf(-s, Rv.w, E3.z);             \
        E3.w = fmaf(c, Qv.w, E3.w); E3.w = fmaf(s, Rv.z, E3.w);              \
        idx = (idx + hh) & 127;                                              \
    }
    for (int u = 0; u < 16; ++u) {
        KD_BODY(Ee0, Ee1, Ee2, Ee3, 2 * u);
        KD_BODY(Eo0, Eo1, Eo2, Eo3, 2 * u + 1);
    }
    KD_BODY(Ee0, Ee1, Ee2, Ee3, 32);
#undef KD_BODY
    __syncthreads();  // all Q/R reads done -> reuse U as Zt
    float* Zt = U;    // [q][h], stride 132
    {
        float* zr = &Zt[(2 * kx0) * 132 + hh];        // row hh
        float* zs = zr + 64;                          // row hh+64
        zr[0*132]  = Ee0.x + Eo0.x;  zs[0*132]  = Ee0.x - Eo0.x;
        zr[1*132]  = Ee0.y + Eo0.y;  zs[1*132]  = Ee0.y - Eo0.y;
        zr[2*132]  = Ee0.z + Eo0.z;  zs[2*132]  = Ee0.z - Eo0.z;
        zr[3*132]  = Ee0.w + Eo0.w;  zs[3*132]  = Ee0.w - Eo0.w;
        zr[4*132]  = Ee1.x + Eo1.x;  zs[4*132]  = Ee1.x - Eo1.x;
        zr[5*132]  = Ee1.y + Eo1.y;  zs[5*132]  = Ee1.y - Eo1.y;
        zr[6*132]  = Ee1.z + Eo1.z;  zs[6*132]  = Ee1.z - Eo1.z;
        zr[7*132]  = Ee1.w + Eo1.w;  zs[7*132]  = Ee1.w - Eo1.w;
        zr[8*132]  = Ee2.x + Eo2.x;  zs[8*132]  = Ee2.x - Eo2.x;
        zr[9*132]  = Ee2.y + Eo2.y;  zs[9*132]  = Ee2.y - Eo2.y;
        zr[10*132] = Ee2.z + Eo2.z;  zs[10*132] = Ee2.z - Eo2.z;
        zr[11*132] = Ee2.w + Eo2.w;  zs[11*132] = Ee2.w - Eo2.w;
        zr[12*132] = Ee3.x + Eo3.x;  zs[12*132] = Ee3.x - Eo3.x;
        zr[13*132] = Ee3.y + Eo3.y;  zs[13*132] = Ee3.y - Eo3.y;
        zr[14*132] = Ee3.z + Eo3.z;  zs[14*132] = Ee3.z - Eo3.z;
        zr[15*132] = Ee3.w + Eo3.w;  zs[15*132] = Ee3.w - Eo3.w;
    }
    __syncthreads();
    // kE GEMM with w-fold: thread (w0 = (t&31)*2, h0 = (t>>5)*16).
    int w0 = (t & 31) * 2;
    int h0 = (t >> 5) * 16;
    float2 We[16], Wo[16];
    #pragma unroll
    for (int j = 0; j < 16; ++j) { We[j] = make_float2(0.f, 0.f); Wo[j] = make_float2(0.f, 0.f); }
#define KE_K(E, K)                                                            \
    {                                                                         \
        const float4* zpe = (const float4*)(&Zt[(2*(K)) * 132 + h0]);         \
        const float4* zpo = (const float4*)(&Zt[(2*(K)+1) * 132 + h0]);       \
        float2 twe = *(const float2*)(&Ts[(2*(K)) * 64 + w0]);                \
        float2 two = *(const float2*)(&Ts[(2*(K)+1) * 64 + w0]);              \
        float4 e0 = zpe[0], e1 = zpe[1], e2 = zpe[2], e3 = zpe[3];            \
        float4 o0 = zpo[0], o1 = zpo[1], o2 = zpo[2], o3 = zpo[3];            \
        E[0].x  = fmaf(e0.x, twe.x, E[0].x);  E[0].x  = fmaf(o0.x, two.x, E[0].x);   \
        E[0].y  = fmaf(e0.x, twe.y, E[0].y);  E[0].y  = fmaf(o0.x, two.y, E[0].y);   \
        E[1].x  = fmaf(e0.y, twe.x, E[1].x);  E[1].x  = fmaf(o0.y, two.x, E[1].x);   \
        E[1].y  = fmaf(e0.y, twe.y, E[1].y);  E[1].y  = fmaf(o0.y, two.y, E[1].y);   \
        E[2].x  = fmaf(e0.z, twe.x, E[2].x);  E[2].x  = fmaf(o0.z, two.x, E[2].x);   \
        E[2].y  = fmaf(e0.z, twe.y, E[2].y);  E[2].y  = fmaf(o0.z, two.y, E[2].y);   \
        E[3].x  = fmaf(e0.w, twe.x, E[3].x);  E[3].x  = fmaf(o0.w, two.x, E[3].x);   \
        E[3].y  = fmaf(e0.w, twe.y, E[3].y);  E[3].y  = fmaf(o0.w, two.y, E[3].y);   \
        E[4].x  = fmaf(e1.x, twe.x, E[4].x);  E[4].x  = fmaf(o1.x, two.x, E[4].x);   \
        E[4].y  = fmaf(e1.x, twe.y, E[4].y);  E[4].y  = fmaf(o1.x, two.y, E[4].y);   \
        E[5].x  = fmaf(e1.y, twe.x, E[5].x);  E[5].x  = fmaf(o1.y, two.x, E[5].x);   \
        E[5].y  = fmaf(e1.y, twe.y, E[5].y);  E[5].y  = fmaf(o1.y, two.y, E[5].y);   \
        E[6].x  = fmaf(e1.z, twe.x, E[6].x);  E[6].x  = fmaf(o1.z, two.x, E[6].x);   \
        E[6].y  = fmaf(e1.z, twe.y, E[6].y);  E[6].y  = fmaf(o1.z, two.y, E[6].y);   \
        E[7].x  = fmaf(e1.w, twe.x, E[7].x);  E[7].x  = fmaf(o1.w, two.x, E[7].x);   \
        E[7].y  = fmaf(e1.w, twe.y, E[7].y);  E[7].y  = fmaf(o1.w, two.y, E[7].y);   \
        E[8].x  = fmaf(e2.x, twe.x, E[8].x);  E[8].x  = fmaf(o2.x, two.x, E[8].x);   \
        E[8].y  = fmaf(e2.x, twe.y, E[8].y);  E[8].y  = fmaf(o2.x, two.y, E[8].y);   \
        E[9].x  = fmaf(e2.y, twe.x, E[9].x);  E[9].x  = fmaf(o2.y, two.x, E[9].x);   \
        E[9].y  = fmaf(e2.y, twe.y, E[9].y);  E[9].y  = fmaf(o2.y, two.y, E[9].y);   \
        E[10].x = fmaf(e2.z, twe.x, E[10].x); E[10].x = fmaf(o2.z, two.x, E[10].x);  \
        E[10].y = fmaf(e2.z, twe.y, E[10].y); E[10].y = fmaf(o2.z, two.y, E[10].y);  \
        E[11].x = fmaf(e2.w, twe.x, E[11].x); E[11].x = fmaf(o2.w, two.x, E[11].x);  \
        E[11].y = fmaf(e2.w, twe.y, E[11].y); E[11].y = fmaf(o2.w, two.y, E[11].y);  \
        E[12].x = fmaf(e3.x, twe.x, E[12].x); E[12].x = fmaf(o3.x, two.x, E[12].x);  \
        E[12].y = fmaf(e3.x, twe.y, E[12].y); E[12].y = fmaf(o3.x, two.y, E[12].y);  \
        E[13].x = fmaf(e3.y, twe.x, E[13].x); E[13].x = fmaf(o3.y, two.x, E[13].x);  \
        E[13].y = fmaf(e3.y, twe.y, E[13].y); E[13].y = fmaf(o3.y, two.y, E[13].y);  \
        E[14].x = fmaf(e3.z, twe.x, E[14].x); E[14].x = fmaf(o3.z, two.x, E[14].x);  \
        E[14].y = fmaf(e3.z, twe.y, E[14].y); E[14].y = fmaf(o3.z, two.y, E[14].y);  \
        E[15].x = fmaf(e3.w, twe.x, E[15].x); E[15].x = fmaf(o3.w, two.x, E[15].x);  \
        E[15].y = fmaf(e3.w, twe.y, E[15].y); E[15].y = fmaf(o3.w, two.y, E[15].y);  \
    }
    #pragma unroll 2
    for (int u = 0; u < 16; ++u) {
        KE_K(We, 2 * u);       // k even
        KE_K(Wo, 2 * u + 1);   // k odd
    }
#undef KE_K
    float bv = bias[(int)(bo & 63)];
    float* ob = out + ((size_t)(bo * 128 + h0)) * 128;
    #pragma unroll
    for (int j = 0; j < 16; ++j) {
        float2 lo = make_float2(We[j].x + Wo[j].x + bv, We[j].y + Wo[j].y + bv);
        float2 hi = make_float2(We[j].x - Wo[j].x + bv, We[j].y - Wo[j].y + bv);
        *(float2*)(ob + (size_t)j * 128 + w0)      = lo;
        *(float2*)(ob + (size_t)j * 128 + w0 + 64) = hi;
    }
}

extern "C" void kernel_launch(void* const* d_in, const int* in_sizes, int n_in,
                              void* d_out, int out_size, void* d_ws, size_t ws_size,
                              hipStream_t stream) {
    (void)in_sizes; (void)n_in; (void)out_size; (void)ws_size;
    const float* x    = (const float*)d_in[0];
    const float* wgt  = (const float*)d_in[1];
    const float* bias = (const float*)d_in[2];
    float* outp   = (float*)d_out;
    char* ws = (char*)d_ws;
    float* bufXF  = (float*)(ws + (48u << 20));     // [48, 64 MiB)
    float* bufYF0 = (float*)(ws);                   // [0, 16 MiB)
    float* bufYF1 = (float*)(ws + (16u << 20));     // [16, 32 MiB)
    hipLaunchKernelGGL(kAB, dim3(1024), dim3(256), 0, stream, x, bufXF);
    hipLaunchKernelGGL(kC, dim3(1024), dim3(256), 0, stream, bufXF, wgt, bufYF0, bufYF1);
    hipLaunchKernelGGL(kDE, dim3(1024), dim3(256), 0, stream, bufYF0, bufYF1, bias, outp);
}

// Round 18
// 111.843 us; speedup vs baseline: 1.0503x; 1.0201x over previous
//
#include <hip/hip_runtime.h>

// FactorizedSpectralConv2d: B=16, CIN=COUT=64, H=W=128, MH=MW=32, super_res=1
// kAB (W-rDFT GEMM + folded H-DFT) -> kC (channel mix, full-line W streaming,
// my-fastest block order for DRAM page locality) -> kDE (inv DFTs + bias).
// ws layout (64 MiB): XF[48,64) ; YF0[0,16) ; YF1[16,32)

__device__ __forceinline__ void build_tab(float* tabs) {
    int t = threadIdx.x;
    if (t < 128) {
        float ang = (float)t * 0.049087385212340517f;  // 2*pi/128
        float s, c;
        sincosf(ang, &s, &c);
        tabs[t] = c;        // cos at [0..127]
        tabs[129 + t] = s;  // sin at [129..256]
    }
}

// ---- kAB: fused W-rDFT (per (b,ci) image) + folded H-DFT ------------------
__global__ __launch_bounds__(256) void kAB(const float* __restrict__ x,
                                           float* __restrict__ XF) {
    __shared__ float tabs[258];
    __shared__ __align__(16) float smem[8704];  // Twid[0,4096)|xeo[4096,8256); later Af[0,8704)
    build_tab(tabs);
    __syncthreads();
    int t = threadIdx.x;
    size_t bc = blockIdx.x;  // b*64+ci, 1024 blocks
    float* Twid = smem;
    float* xeo  = smem + 4096;
    #pragma unroll
    for (int i = 0; i < 16; ++i) {
        int e = t + i * 256;
        int w = e >> 6, q = e & 63, kx = q >> 1;
        int idx = (w * kx) & 127;
        Twid[e] = (q & 1) ? -tabs[129 + idx] : tabs[idx];
    }
    const float* xb = x + bc * 16384;
    int th = t & 31;   // h in {2th, 2th+1, 2th+64, 2th+65}
    int tq = t >> 5;   // q in [8tq, 8tq+8)
    int q0 = tq * 8;
    int wl4 = (t & 3) * 4;  // staging lanes
    int hb  = t >> 2;
    float4 rlo0, rhi0, rlo1, rhi1;
    auto loadR = [&](int ph) {
        rlo0 = *(const float4*)(xb + hb * 128 + ph * 16 + wl4);
        rhi0 = *(const float4*)(xb + hb * 128 + ph * 16 + wl4 + 64);
        rlo1 = *(const float4*)(xb + (64 + hb) * 128 + ph * 16 + wl4);
        rhi1 = *(const float4*)(xb + (64 + hb) * 128 + ph * 16 + wl4 + 64);
    };
    auto writeR = [&]() {
        int h0 = hb, h1 = 64 + hb;
        *(float2*)(&xeo[(wl4+0)*260 + 2*h0]) = make_float2(rlo0.x+rhi0.x, rlo0.x-rhi0.x);
        *(float2*)(&xeo[(wl4+1)*260 + 2*h0]) = make_float2(rlo0.y+rhi0.y, rlo0.y-rhi0.y);
        *(float2*)(&xeo[(wl4+2)*260 + 2*h0]) = make_float2(rlo0.z+rhi0.z, rlo0.z-rhi0.z);
        *(float2*)(&xeo[(wl4+3)*260 + 2*h0]) = make_float2(rlo0.w+rhi0.w, rlo0.w-rhi0.w);
        *(float2*)(&xeo[(wl4+0)*260 + 2*h1]) = make_float2(rlo1.x+rhi1.x, rlo1.x-rhi1.x);
        *(float2*)(&xeo[(wl4+1)*260 + 2*h1]) = make_float2(rlo1.y+rhi1.y, rlo1.y-rhi1.y);
        *(float2*)(&xeo[(wl4+2)*260 + 2*h1]) = make_float2(rlo1.z+rhi1.z, rlo1.z-rhi1.z);
        *(float2*)(&xeo[(wl4+3)*260 + 2*h1]) = make_float2(rlo1.w+rhi1.w, rlo1.w-rhi1.w);
    };
    loadR(0);
    writeR();
    float4 acc[8];
    #pragma unroll
    for (int j = 0; j < 8; ++j) acc[j] = make_float4(0.f, 0.f, 0.f, 0.f);
    __syncthreads();  // xeo(0) ready
    for (int ph = 0; ph < 4; ++ph) {
        if (ph < 3) loadR(ph + 1);  // loads fly under compute
        #pragma unroll 4
        for (int wl = 0; wl < 16; ++wl) {
            int w = ph * 16 + wl;
            const float* xr = &xeo[wl * 260 + 4 * th];
            float4 d0  = *(const float4*)(xr);         // ve,vo for h=2th, 2th+1
            float4 d1  = *(const float4*)(xr + 128);   // ve,vo for h+64
            float4 tw0 = *(const float4*)(&Twid[w * 64 + q0]);
            float4 tw1 = *(const float4*)(&Twid[w * 64 + q0 + 4]);
            acc[0].x = fmaf(d0.x, tw0.x, acc[0].x); acc[0].y = fmaf(d0.x, tw0.y, acc[0].y);
            acc[0].z = fmaf(d0.y, tw0.z, acc[0].z); acc[0].w = fmaf(d0.y, tw0.w, acc[0].w);
            acc[1].x = fmaf(d0.x, tw1.x, acc[1].x); acc[1].y = fmaf(d0.x, tw1.y, acc[1].y);
            acc[1].z = fmaf(d0.y, tw1.z, acc[1].z); acc[1].w = fmaf(d0.y, tw1.w, acc[1].w);
            acc[2].x = fmaf(d0.z, tw0.x, acc[2].x); acc[2].y = fmaf(d0.z, tw0.y, acc[2].y);
            acc[2].z = fmaf(d0.w, tw0.z, acc[2].z); acc[2].w = fmaf(d0.w, tw0.w, acc[2].w);
            acc[3].x = fmaf(d0.z, tw1.x, acc[3].x); acc[3].y = fmaf(d0.z, tw1.y, acc[3].y);
            acc[3].z = fmaf(d0.w, tw1.z, acc[3].z); acc[3].w = fmaf(d0.w, tw1.w, acc[3].w);
            acc[4].x = fmaf(d1.x, tw0.x, acc[4].x); acc[4].y = fmaf(d1.x, tw0.y, acc[4].y);
            acc[4].z = fmaf(d1.y, tw0.z, acc[4].z); acc[4].w = fmaf(d1.y, tw0.w, acc[4].w);
            acc[5].x = fmaf(d1.x, tw1.x, acc[5].x); acc[5].y = fmaf(d1.x, tw1.y, acc[5].y);
            acc[5].z = fmaf(d1.y, tw1.z, acc[5].z); acc[5].w = fmaf(d1.y, tw1.w, acc[5].w);
            acc[6].x = fmaf(d1.z, tw0.x, acc[6].x); acc[6].y = fmaf(d1.z, tw0.y, acc[6].y);
            acc[6].z = fmaf(d1.w, tw0.z, acc[6].z); acc[6].w = fmaf(d1.w, tw0.w, acc[6].w);
            acc[7].x = fmaf(d1.z, tw1.x, acc[7].x); acc[7].y = fmaf(d1.z, tw1.y, acc[7].y);
            acc[7].z = fmaf(d1.w, tw1.z, acc[7].z); acc[7].w = fmaf(d1.w, tw1.w, acc[7].w);
        }
        __syncthreads();
        if (ph < 3) {
            writeR();
            __syncthreads();
        }
    }
    // In-register (h, h+64) fold -> Af planes, row stride 68.
    float* Af = smem;
    {
        int base = th * 68 + q0;
        *(float4*)(&Af[base])          = make_float4(acc[0].x+acc[4].x, acc[0].y+acc[4].y, acc[0].z+acc[4].z, acc[0].w+acc[4].w);
        *(float4*)(&Af[base + 4])      = make_float4(acc[1].x+acc[5].x, acc[1].y+acc[5].y, acc[1].z+acc[5].z, acc[1].w+acc[5].w);
        *(float4*)(&Af[2176 + base])   = make_float4(acc[0].x-acc[4].x, acc[0].y-acc[4].y, acc[0].z-acc[4].z, acc[0].w-acc[4].w);
        *(float4*)(&Af[2176 + base+4]) = make_float4(acc[1].x-acc[5].x, acc[1].y-acc[5].y, acc[1].z-acc[5].z, acc[1].w-acc[5].w);
        *(float4*)(&Af[4352 + base])   = make_float4(acc[2].x+acc[6].x, acc[2].y+acc[6].y, acc[2].z+acc[6].z, acc[2].w+acc[6].w);
        *(float4*)(&Af[4352 + base+4]) = make_float4(acc[3].x+acc[7].x, acc[3].y+acc[7].y, acc[3].z+acc[7].z, acc[3].w+acc[7].w);
        *(float4*)(&Af[6528 + base])   = make_float4(acc[2].x-acc[6].x, acc[2].y-acc[6].y, acc[2].z-acc[6].z, acc[2].w-acc[6].w);
        *(float4*)(&Af[6528 + base+4]) = make_float4(acc[3].x-acc[7].x, acc[3].y-acc[7].y, acc[3].z-acc[7].z, acc[3].w-acc[7].w);
    }
    __syncthreads();
    // ---- kB compute part (twiddles via rotation recurrence) ----
    {
        int k = t & 31, kxg = t >> 5;
        int kx0 = kxg * 4;
        int sig = k & 1;
        const float* pe = Af + sig * 2176;
        const float* po = Af + 4352 + sig * 2176;
        int a2 = (2 * k) & 127;
        float ca = tabs[a2], sa = tabs[129 + a2];
        float ce = 1.f, se = 0.f;
        float co_ = tabs[k], so_ = tabs[129 + k];
        float4 P1 = {0,0,0,0}, P2 = {0,0,0,0}, P3 = {0,0,0,0}, P4 = {0,0,0,0};
        for (int m = 0; m < 32; ++m) {
            float4 ae01 = *(const float4*)(pe + m * 68 + 2 * kx0);
            float4 ae23 = *(const float4*)(pe + m * 68 + 2 * kx0 + 4);
            float4 ao01 = *(const float4*)(po + m * 68 + 2 * kx0);
            float4 ao23 = *(const float4*)(po + m * 68 + 2 * kx0 + 4);
            P1.x = fmaf(ae01.x, ce, P1.x); P1.x = fmaf(ao01.x, co_, P1.x);
            P2.x = fmaf(ae01.y, se, P2.x); P2.x = fmaf(ao01.y, so_, P2.x);
            P3.x = fmaf(ae01.y, ce, P3.x); P3.x = fmaf(ao01.y, co_, P3.x);
            P4.x = fmaf(ae01.x, se, P4.x); P4.x = fmaf(ao01.x, so_, P4.x);
            P1.y = fmaf(ae01.z, ce, P1.y); P1.y = fmaf(ao01.z, co_, P1.y);
            P2.y = fmaf(ae01.w, se, P2.y); P2.y = fmaf(ao01.w, so_, P2.y);
            P3.y = fmaf(ae01.w, ce, P3.y); P3.y = fmaf(ao01.w, co_, P3.y);
            P4.y = fmaf(ae01.z, se, P4.y); P4.y = fmaf(ao01.z, so_, P4.y);
            P1.z = fmaf(ae23.x, ce, P1.z); P1.z = fmaf(ao23.x, co_, P1.z);
            P2.z = fmaf(ae23.y, se, P2.z); P2.z = fmaf(ao23.y, so_, P2.z);
            P3.z = fmaf(ae23.y, ce, P3.z); P3.z = fmaf(ao23.y, co_, P3.z);
            P4.z = fmaf(ae23.x, se, P4.z); P4.z = fmaf(ao23.x, so_, P4.z);
            P1.w = fmaf(ae23.z, ce, P1.w); P1.w = fmaf(ao23.z, co_, P1.w);
            P2.w = fmaf(ae23.w, se, P2.w); P2.w = fmaf(ao23.w, so_, P2.w);
            P3.w = fmaf(ae23.w, ce, P3.w); P3.w = fmaf(ao23.w, co_, P3.w);
            P4.w = fmaf(ae23.z, se, P4.w); P4.w = fmaf(ao23.z, so_, P4.w);
            float t1 = se * sa, t2 = ce * sa;
            float cen = fmaf(ce, ca, -t1);
            float sen = fmaf(se, ca, t2);
            ce = cen; se = sen;
            float t3 = so_ * sa, t4 = co_ * sa;
            float con = fmaf(co_, ca, -t3);
            float son = fmaf(so_, ca, t4);
            co_ = con; so_ = son;
        }
        float* xfb = XF + bc * 4096;
        *(float4*)(xfb + (k * 32 + kx0) * 2) =
            make_float4(P1.x + P2.x, P3.x - P4.x, P1.y + P2.y, P3.y - P4.y);
        *(float4*)(xfb + (k * 32 + kx0) * 2 + 4) =
            make_float4(P1.z + P2.z, P3.z - P4.z, P1.w + P2.w, P3.w - P4.w);
        if (k) {
            *(float4*)(xfb + ((64 - k) * 32 + kx0) * 2) =
                make_float4(P1.x - P2.x, P3.x + P4.x, P1.y - P2.y, P3.y + P4.y);
            *(float4*)(xfb + ((64 - k) * 32 + kx0) * 2 + 4) =
                make_float4(P1.z - P2.z, P3.z + P4.z, P1.w - P2.w, P3.w + P4.w);
        }
        if (t < 32) {
            int kx = t;
            float re = 0.f, im = 0.f;
            #pragma unroll 8
            for (int m = 0; m < 32; ++m) {
                float2 aep = *(const float2*)(&Af[       m * 68 + 2 * kx]);
                float2 aop = *(const float2*)(&Af[4352 + m * 68 + 2 * kx]);
                float sg = (m & 1) ? -1.f : 1.f;
                re = fmaf(sg, aep.x - aop.y, re);
                im = fmaf(sg, aep.y + aop.x, im);
            }
            xfb[(32 * 32 + kx) * 2]     = re;
            xfb[(32 * 32 + kx) * 2 + 1] = im;
        }
    }
}

// ---- kC v8: full-line W streaming + my-fastest block order ----------------
// bid = c<<9 | cot<<6 | cih<<5 | my (1024 blocks): the 32 blocks sharing a
// W row-set (all my) are consecutive -> co-resident -> DRAM page-hit streaks.
// Thread=(co_l 8, mx 32), acc over all 16 b; ci chunked by 4; async dbuf.
__global__ __launch_bounds__(256) void kC(const float* __restrict__ XF,
                                          const float* __restrict__ Wgt,
                                          float* __restrict__ YF0,
                                          float* __restrict__ YF1) {
    __shared__ __align__(16) float Xb[2][4096];  // [buf][ci_l 4][b 16][mx 32] cplx
    __shared__ __align__(16) float Wb[2][2048];  // [buf][pl 2][ci_l 4][co_l 8][mx 32]
    int t = threadIdx.x;
    int lane = t & 63, wid = t >> 6;
    int bid = blockIdx.x;
    int my  = bid & 31;
    int cih = (bid >> 5) & 1;
    int cot = (bid >> 6) & 7;
    int c   = bid >> 9;
    int co0 = cot * 8;
    int slotbase = (c * 32 + my) * 32;  // + mx
    int mx   = t & 31;
    int co_l = t >> 5;
    int co = co0 + co_l;
    int ci0 = cih * 32;
    float2 acc[16];
    #pragma unroll
    for (int i = 0; i < 16; ++i) acc[i] = make_float2(0.f, 0.f);
    const float* wbase = Wgt + (size_t)c * 4194304 + (size_t)my * 32;
    auto stage = [&](int cc, int buf) {
        // X chunk: 16 KB = 16 insts x 1 KB; wave wid issues [4w, 4w+4)
        #pragma unroll
        for (int i = 0; i < 4; ++i) {
            int inst = wid * 4 + i;
            int u = inst * 64 + lane;             // [ci_l 4][b 16][mxp 16]
            int mxp = u & 15, b = (u >> 4) & 15, ci_l = u >> 8;
            int ci = ci0 + cc * 4 + ci_l;
            const float* g = XF + ((size_t)(b * 64 + ci) * 2048 + slotbase + mxp * 2) * 2;
            float* l = Xb[buf] + inst * 256;
            __builtin_amdgcn_global_load_lds(g, l, 16, 0, 0);
        }
        // W chunk: 8 KB = 8 insts x 1 KB; wave wid issues [2w, 2w+2)
        #pragma unroll
        for (int i = 0; i < 2; ++i) {
            int inst = wid * 2 + i;
            int u = inst * 64 + lane;             // [pl 2][ci_l 4][co_l 8][mx4 8]
            int mx4 = u & 7, col = (u >> 3) & 7, ci_l = (u >> 6) & 3, pl = u >> 8;
            const float* g = wbase + (size_t)pl * 8388608
                           + ((size_t)(ci0 + cc * 4 + ci_l) * 64 + co0 + col) * 1024
                           + mx4 * 4;
            float* l = Wb[buf] + inst * 256;
            __builtin_amdgcn_global_load_lds(g, l, 16, 0, 0);
        }
    };
#define KC_COMPUTE(BUF)                                                      \
    {                                                                        \
        _Pragma("unroll")                                                    \
        for (int j = 0; j < 4; ++j) {                                        \
            float wre = Wb[BUF][(j * 8 + co_l) * 32 + mx];                   \
            float wim = Wb[BUF][1024 + (j * 8 + co_l) * 32 + mx];            \
            _Pragma("unroll")                                                \
            for (int b = 0; b < 16; ++b) {                                   \
                float2 xv = *(const float2*)(&Xb[BUF][((j * 16 + b) * 32 + mx) * 2]); \
                acc[b].x = fmaf(xv.x, wre, acc[b].x);                        \
                acc[b].x = fmaf(-xv.y, wim, acc[b].x);                       \
                acc[b].y = fmaf(xv.x, wim, acc[b].y);                        \
                acc[b].y = fmaf(xv.y, wre, acc[b].y);                        \
            }                                                                \
        }                                                                    \
    }
    stage(0, 0);
    __syncthreads();
    stage(1, 1); KC_COMPUTE(0); __syncthreads();
    stage(2, 0); KC_COMPUTE(1); __syncthreads();
    stage(3, 1); KC_COMPUTE(0); __syncthreads();
    stage(4, 0); KC_COMPUTE(1); __syncthreads();
    stage(5, 1); KC_COMPUTE(0); __syncthreads();
    stage(6, 0); KC_COMPUTE(1); __syncthreads();
    stage(7, 1); KC_COMPUTE(0); __syncthreads();
    KC_COMPUTE(1);
#undef KC_COMPUTE
    float* YF = cih ? YF1 : YF0;
    #pragma unroll
    for (int b = 0; b < 16; ++b) {
        *(float2*)(YF + ((size_t)(b * 64 + co) * 2048 + slotbase + mx) * 2) = acc[b];
    }
}

// ---- kDE: fused inv H-DFT (folded) + inv W-rDFT (w-folded) + bias ---------
__global__ __launch_bounds__(256) void kDE(const float* __restrict__ YF0,
                                           const float* __restrict__ YF1,
                                           const float* __restrict__ bias,
                                           float* __restrict__ out) {
    __shared__ float tabs[258];
    __shared__ __align__(16) float Ts[4096];  // [q 64][w 64], 16 KB
    __shared__ __align__(16) float U[8448];   // Q[0,2112)+R[2112,4224) -> Zt[64][132]
    build_tab(tabs);
    __syncthreads();
    int t = threadIdx.x;
    size_t bo = blockIdx.x;
    const float inv = 6.103515625e-05f;  // 1/16384
    #pragma unroll
    for (int i = 0; i < 16; ++i) {
        int e = t + i * 256;
        int q = e >> 6, w = e & 63;
        int k = q >> 1;
        int idx = (k * w) & 127;
        float val;
        if (q == 0)      val = inv;
        else if (q == 1) val = 0.f;
        else if (q & 1)  val = -2.f * inv * tabs[129 + idx];
        else             val =  2.f * inv * tabs[idx];
        Ts[e] = val;
    }
    float* Qs = U;
    float* Rs = U + 2112;
    const float* y0 = YF0 + bo * 4096;
    const float* y1 = YF1 + bo * 4096;
    for (int u = t; u < 528; u += 256) {
        int k = u >> 4, kxf = (u & 15) * 4;
        float4 a0 = *(const float4*)(y0 + k * 64 + kxf);
        float4 a1 = *(const float4*)(y1 + k * 64 + kxf);
        float4 a = make_float4(a0.x+a1.x, a0.y+a1.y, a0.z+a1.z, a0.w+a1.w);
        float4 Q, R;
        if (k == 0) { Q = a; R = make_float4(0.f, 0.f, 0.f, 0.f); }
        else if (k == 32) { Q = a; R = make_float4(-a.x, -a.y, -a.z, -a.w); }
        else {
            float4 b0 = *(const float4*)(y0 + (64 - k) * 64 + kxf);
            float4 b1 = *(const float4*)(y1 + (64 - k) * 64 + kxf);
            float4 bb = make_float4(b0.x+b1.x, b0.y+b1.y, b0.z+b1.z, b0.w+b1.w);
            Q = make_float4(a.x+bb.x, a.y+bb.y, a.z+bb.z, a.w+bb.w);
            R = make_float4(a.x-bb.x, a.y-bb.y, a.z-bb.z, a.w-bb.w);
        }
        *(float4*)(&Qs[k * 64 + kxf]) = Q;
        *(float4*)(&Rs[k * 64 + kxf]) = R;
    }
    __syncthreads();
    int hh = t >> 2;
    int kx0 = (t & 3) * 8;
    float4 Ee0 = {0,0,0,0}, Ee1 = {0,0,0,0}, Ee2 = {0,0,0,0}, Ee3 = {0,0,0,0};
    float4 Eo0 = {0,0,0,0}, Eo1 = {0,0,0,0}, Eo2 = {0,0,0,0}, Eo3 = {0,0,0,0};
    int idx = 0;
#define KD_BODY(E0, E1, E2, E3, kk)                                          \
    {                                                                        \
        float c = tabs[idx], s = tabs[129 + idx];                            \
        const float4* Qp = (const float4*)(&Qs[(kk) * 64 + kx0 * 2]);        \
        const float4* Rp = (const float4*)(&Rs[(kk) * 64 + kx0 * 2]);        \
        float4 Qv, Rv;                                                       \
        Qv = Qp[0]; Rv = Rp[0];                                              \
        E0.x = fmaf(c, Qv.x, E0.x); E0.x = fmaf(-s, Rv.y, E0.x);             \
        E0.y = fmaf(c, Qv.y, E0.y); E0.y = fmaf(s, Rv.x, E0.y);              \
        E0.z = fmaf(c, Qv.z, E0.z); E0.z = fmaf(-s, Rv.w, E0.z);             \
        E0.w = fmaf(c, Qv.w, E0.w); E0.w = fmaf(s, Rv.z, E0.w);              \
        Qv = Qp[1]; Rv = Rp[1];                                              \
        E1.x = fmaf(c, Qv.x, E1.x); E1.x = fmaf(-s, Rv.y, E1.x);             \
        E1.y = fmaf(c, Qv.y, E1.y); E1.y = fmaf(s, Rv.x, E1.y);              \
        E1.z = fmaf(c, Qv.z, E1.z); E1.z = fmaf(-s, Rv.w, E1.z);             \
        E1.w = fmaf(c, Qv.w, E1.w); E1.w = fmaf(s, Rv.z, E1.w);              \
        Qv = Qp[2]; Rv = Rp[2];                                              \
        E2.x = fmaf(c, Qv.x, E2.x); E2.x = fmaf(-s, Rv.y, E2.x);             \
        E2.y = fmaf(c, Qv.y, E2.y); E2.y = fmaf(s, Rv.x, E2.y);              \
        E2.z = fmaf(c, Qv.z, E2.z); E2.z = fmaf(-s, Rv.w, E2.z);             \
        E2.w = fmaf(c, Qv.w, E2.w); E2.w = fmaf(s, Rv.z, E2.w);              \
        Qv = Qp[3]; Rv = Rp[3];                                              \
        E3.x = fmaf(c, Qv.x, E3.x); E3.x = fmaf(-s, Rv.y, E3.x);             \
        E3.y = fmaf(c, Qv.y, E3.y); E3.y = fmaf(s, Rv.x, E3.y);              \
        E3.z = fmaf(c, Qv.z, E3.z); E3.z = fmaf(-s, Rv.w, E3.z);             \
        E3.w = fmaf(c, Qv.w, E3.w); E3.w = fmaf(s, Rv.z, E3.w);              \
        idx = (idx + hh) & 127;                                              \
    }
    for (int u = 0; u < 16; ++u) {
        KD_BODY(Ee0, Ee1, Ee2, Ee3, 2 * u);
        KD_BODY(Eo0, Eo1, Eo2, Eo3, 2 * u + 1);
    }
    KD_BODY(Ee0, Ee1, Ee2, Ee3, 32);
#undef KD_BODY
    __syncthreads();  // all Q/R reads done -> reuse U as Zt
    float* Zt = U;    // [q][h], stride 132
    {
        float* zr = &Zt[(2 * kx0) * 132 + hh];        // row hh
        float* zs = zr + 64;                          // row hh+64
        zr[0*132]  = Ee0.x + Eo0.x;  zs[0*132]  = Ee0.x - Eo0.x;
        zr[1*132]  = Ee0.y + Eo0.y;  zs[1*132]  = Ee0.y - Eo0.y;
        zr[2*132]  = Ee0.z + Eo0.z;  zs[2*132]  = Ee0.z - Eo0.z;
        zr[3*132]  = Ee0.w + Eo0.w;  zs[3*132]  = Ee0.w - Eo0.w;
        zr[4*132]  = Ee1.x + Eo1.x;  zs[4*132]  = Ee1.x - Eo1.x;
        zr[5*132]  = Ee1.y + Eo1.y;  zs[5*132]  = Ee1.y - Eo1.y;
        zr[6*132]  = Ee1.z + Eo1.z;  zs[6*132]  = Ee1.z - Eo1.z;
        zr[7*132]  = Ee1.w + Eo1.w;  zs[7*132]  = Ee1.w - Eo1.w;
        zr[8*132]  = Ee2.x + Eo2.x;  zs[8*132]  = Ee2.x - Eo2.x;
        zr[9*132]  = Ee2.y + Eo2.y;  zs[9*132]  = Ee2.y - Eo2.y;
        zr[10*132] = Ee2.z + Eo2.z;  zs[10*132] = Ee2.z - Eo2.z;
        zr[11*132] = Ee2.w + Eo2.w;  zs[11*132] = Ee2.w - Eo2.w;
        zr[12*132] = Ee3.x + Eo3.x;  zs[12*132] = Ee3.x - Eo3.x;
        zr[13*132] = Ee3.y + Eo3.y;  zs[13*132] = Ee3.y - Eo3.y;
        zr[14*132] = Ee3.z + Eo3.z;  zs[14*132] = Ee3.z - Eo3.z;
        zr[15*132] = Ee3.w + Eo3.w;  zs[15*132] = Ee3.w - Eo3.w;
    }
    __syncthreads();
    // kE GEMM with w-fold: thread (w0 = (t&31)*2, h0 = (t>>5)*16).
    int w0 = (t & 31) * 2;
    int h0 = (t >> 5) * 16;
    float2 We[16], Wo[16];
    #pragma unroll
    for (int j = 0; j < 16; ++j) { We[j] = make_float2(0.f, 0.f); Wo[j] = make_float2(0.f, 0.f); }
#define KE_K(E, K)                                                            \
    {                                                                         \
        const float4* zpe = (const float4*)(&Zt[(2*(K)) * 132 + h0]);         \
        const float4* zpo = (const float4*)(&Zt[(2*(K)+1) * 132 + h0]);       \
        float2 twe = *(const float2*)(&Ts[(2*(K)) * 64 + w0]);                \
        float2 two = *(const float2*)(&Ts[(2*(K)+1) * 64 + w0]);              \
        float4 e0 = zpe[0], e1 = zpe[1], e2 = zpe[2], e3 = zpe[3];            \
        float4 o0 = zpo[0], o1 = zpo[1], o2 = zpo[2], o3 = zpo[3];            \
        E[0].x  = fmaf(e0.x, twe.x, E[0].x);  E[0].x  = fmaf(o0.x, two.x, E[0].x);   \
        E[0].y  = fmaf(e0.x, twe.y, E[0].y);  E[0].y  = fmaf(o0.x, two.y, E[0].y);   \
        E[1].x  = fmaf(e0.y, twe.x, E[1].x);  E[1].x  = fmaf(o0.y, two.x, E[1].x);   \
        E[1].y  = fmaf(e0.y, twe.y, E[1].y);  E[1].y  = fmaf(o0.y, two.y, E[1].y);   \
        E[2].x  = fmaf(e0.z, twe.x, E[2].x);  E[2].x  = fmaf(o0.z, two.x, E[2].x);   \
        E[2].y  = fmaf(e0.z, twe.y, E[2].y);  E[2].y  = fmaf(o0.z, two.y, E[2].y);   \
        E[3].x  = fmaf(e0.w, twe.x, E[3].x);  E[3].x  = fmaf(o0.w, two.x, E[3].x);   \
        E[3].y  = fmaf(e0.w, twe.y, E[3].y);  E[3].y  = fmaf(o0.w, two.y, E[3].y);   \
        E[4].x  = fmaf(e1.x, twe.x, E[4].x);  E[4].x  = fmaf(o1.x, two.x, E[4].x);   \
        E[4].y  = fmaf(e1.x, twe.y, E[4].y);  E[4].y  = fmaf(o1.x, two.y, E[4].y);   \
        E[5].x  = fmaf(e1.y, twe.x, E[5].x);  E[5].x  = fmaf(o1.y, two.x, E[5].x);   \
        E[5].y  = fmaf(e1.y, twe.y, E[5].y);  E[5].y  = fmaf(o1.y, two.y, E[5].y);   \
        E[6].x  = fmaf(e1.z, twe.x, E[6].x);  E[6].x  = fmaf(o1.z, two.x, E[6].x);   \
        E[6].y  = fmaf(e1.z, twe.y, E[6].y);  E[6].y  = fmaf(o1.z, two.y, E[6].y);   \
        E[7].x  = fmaf(e1.w, twe.x, E[7].x);  E[7].x  = fmaf(o1.w, two.x, E[7].x);   \
        E[7].y  = fmaf(e1.w, twe.y, E[7].y);  E[7].y  = fmaf(o1.w, two.y, E[7].y);   \
        E[8].x  = fmaf(e2.x, twe.x, E[8].x);  E[8].x  = fmaf(o2.x, two.x, E[8].x);   \
        E[8].y  = fmaf(e2.x, twe.y, E[8].y);  E[8].y  = fmaf(o2.x, two.y, E[8].y);   \
        E[9].x  = fmaf(e2.y, twe.x, E[9].x);  E[9].x  = fmaf(o2.y, two.x, E[9].x);   \
        E[9].y  = fmaf(e2.y, twe.y, E[9].y);  E[9].y  = fmaf(o2.y, two.y, E[9].y);   \
        E[10].x = fmaf(e2.z, twe.x, E[10].x); E[10].x = fmaf(o2.z, two.x, E[10].x);  \
        E[10].y = fmaf(e2.z, twe.y, E[10].y); E[10].y = fmaf(o2.z, two.y, E[10].y);  \
        E[11].x = fmaf(e2.w, twe.x, E[11].x); E[11].x = fmaf(o2.w, two.x, E[11].x);  \
        E[11].y = fmaf(e2.w, twe.y, E[11].y); E[11].y = fmaf(o2.w, two.y, E[11].y);  \
        E[12].x = fmaf(e3.x, twe.x, E[12].x); E[12].x = fmaf(o3.x, two.x, E[12].x);  \
        E[12].y = fmaf(e3.x, twe.y, E[12].y); E[12].y = fmaf(o3.x, two.y, E[12].y);  \
        E[13].x = fmaf(e3.y, twe.x, E[13].x); E[13].x = fmaf(o3.y, two.x, E[13].x);  \
        E[13].y = fmaf(e3.y, twe.y, E[13].y); E[13].y = fmaf(o3.y, two.y, E[13].y);  \
        E[14].x = fmaf(e3.z, twe.x, E[14].x); E[14].x = fmaf(o3.z, two.x, E[14].x);  \
        E[14].y = fmaf(e3.z, twe.y, E[14].y); E[14].y = fmaf(o3.z, two.y, E[14].y);  \
        E[15].x = fmaf(e3.w, twe.x, E[15].x); E[15].x = fmaf(o3.w, two.x, E[15].x);  \
        E[15].y = fmaf(e3.w, twe.y, E[15].y); E[15].y = fmaf(o3.w, two.y, E[15].y);  \
    }
    #pragma unroll 2
    for (int u = 0; u < 16; ++u) {
        KE_K(We, 2 * u);       // k even
        KE_K(Wo, 2 * u + 1);   // k odd
    }
#undef KE_K
    float bv = bias[(int)(bo & 63)];
    float* ob = out + ((size_t)(bo * 128 + h0)) * 128;
    #pragma unroll
    for (int j = 0; j < 16; ++j) {
        float2 lo = make_float2(We[j].x + Wo[j].x + bv, We[j].y + Wo[j].y + bv);
        float2 hi = make_float2(We[j].x - Wo[j].x + bv, We[j].y - Wo[j].y + bv);
        *(float2*)(ob + (size_t)j * 128 + w0)      = lo;
        *(float2*)(ob + (size_t)j * 128 + w0 + 64) = hi;
    }
}

extern "C" void kernel_launch(void* const* d_in, const int* in_sizes, int n_in,
                              void* d_out, int out_size, void* d_ws, size_t ws_size,
                              hipStream_t stream) {
    (void)in_sizes; (void)n_in; (void)out_size; (void)ws_size;
    const float* x    = (const float*)d_in[0];
    const float* wgt  = (const float*)d_in[1];
    const float* bias = (const float*)d_in[2];
    float* outp   = (float*)d_out;
    char* ws = (char*)d_ws;
    float* bufXF  = (float*)(ws + (48u << 20));     // [48, 64 MiB)
    float* bufYF0 = (float*)(ws);                   // [0, 16 MiB)
    float* bufYF1 = (float*)(ws + (16u << 20));     // [16, 32 MiB)
    hipLaunchKernelGGL(kAB, dim3(1024), dim3(256), 0, stream, x, bufXF);
    hipLaunchKernelGGL(kC, dim3(1024), dim3(256), 0, stream, bufXF, wgt, bufYF0, bufYF1);
    hipLaunchKernelGGL(kDE, dim3(1024), dim3(256), 0, stream, bufYF0, bufYF1, bias, outp);
}

// Round 19
// 105.690 us; speedup vs baseline: 1.1115x; 1.0582x over previous
//
#include <hip/hip_runtime.h>

// FactorizedSpectralConv2d: B=16, CIN=COUT=64, H=W=128, MH=MW=32, super_res=1
// kAB (W-rDFT GEMM + folded H-DFT) -> kC (channel mix, full-line W streaming,
// my-fastest block order) -> kDE v2 (inv DFTs via phasor recurrences + bias).
// ws layout (64 MiB): XF[48,64) ; YF0[0,16) ; YF1[16,32)

__device__ __forceinline__ void build_tab(float* tabs) {
    int t = threadIdx.x;
    if (t < 128) {
        float ang = (float)t * 0.049087385212340517f;  // 2*pi/128
        float s, c;
        sincosf(ang, &s, &c);
        tabs[t] = c;        // cos at [0..127]
        tabs[129 + t] = s;  // sin at [129..256]
    }
}

// ---- kAB: fused W-rDFT (per (b,ci) image) + folded H-DFT ------------------
__global__ __launch_bounds__(256) void kAB(const float* __restrict__ x,
                                           float* __restrict__ XF) {
    __shared__ float tabs[258];
    __shared__ __align__(16) float smem[8704];  // Twid[0,4096)|xeo[4096,8256); later Af[0,8704)
    build_tab(tabs);
    __syncthreads();
    int t = threadIdx.x;
    size_t bc = blockIdx.x;  // b*64+ci, 1024 blocks
    float* Twid = smem;
    float* xeo  = smem + 4096;
    #pragma unroll
    for (int i = 0; i < 16; ++i) {
        int e = t + i * 256;
        int w = e >> 6, q = e & 63, kx = q >> 1;
        int idx = (w * kx) & 127;
        Twid[e] = (q & 1) ? -tabs[129 + idx] : tabs[idx];
    }
    const float* xb = x + bc * 16384;
    int th = t & 31;   // h in {2th, 2th+1, 2th+64, 2th+65}
    int tq = t >> 5;   // q in [8tq, 8tq+8)
    int q0 = tq * 8;
    int wl4 = (t & 3) * 4;  // staging lanes
    int hb  = t >> 2;
    float4 rlo0, rhi0, rlo1, rhi1;
    auto loadR = [&](int ph) {
        rlo0 = *(const float4*)(xb + hb * 128 + ph * 16 + wl4);
        rhi0 = *(const float4*)(xb + hb * 128 + ph * 16 + wl4 + 64);
        rlo1 = *(const float4*)(xb + (64 + hb) * 128 + ph * 16 + wl4);
        rhi1 = *(const float4*)(xb + (64 + hb) * 128 + ph * 16 + wl4 + 64);
    };
    auto writeR = [&]() {
        int h0 = hb, h1 = 64 + hb;
        *(float2*)(&xeo[(wl4+0)*260 + 2*h0]) = make_float2(rlo0.x+rhi0.x, rlo0.x-rhi0.x);
        *(float2*)(&xeo[(wl4+1)*260 + 2*h0]) = make_float2(rlo0.y+rhi0.y, rlo0.y-rhi0.y);
        *(float2*)(&xeo[(wl4+2)*260 + 2*h0]) = make_float2(rlo0.z+rhi0.z, rlo0.z-rhi0.z);
        *(float2*)(&xeo[(wl4+3)*260 + 2*h0]) = make_float2(rlo0.w+rhi0.w, rlo0.w-rhi0.w);
        *(float2*)(&xeo[(wl4+0)*260 + 2*h1]) = make_float2(rlo1.x+rhi1.x, rlo1.x-rhi1.x);
        *(float2*)(&xeo[(wl4+1)*260 + 2*h1]) = make_float2(rlo1.y+rhi1.y, rlo1.y-rhi1.y);
        *(float2*)(&xeo[(wl4+2)*260 + 2*h1]) = make_float2(rlo1.z+rhi1.z, rlo1.z-rhi1.z);
        *(float2*)(&xeo[(wl4+3)*260 + 2*h1]) = make_float2(rlo1.w+rhi1.w, rlo1.w-rhi1.w);
    };
    loadR(0);
    writeR();
    float4 acc[8];
    #pragma unroll
    for (int j = 0; j < 8; ++j) acc[j] = make_float4(0.f, 0.f, 0.f, 0.f);
    __syncthreads();  // xeo(0) ready
    for (int ph = 0; ph < 4; ++ph) {
        if (ph < 3) loadR(ph + 1);  // loads fly under compute
        #pragma unroll 4
        for (int wl = 0; wl < 16; ++wl) {
            int w = ph * 16 + wl;
            const float* xr = &xeo[wl * 260 + 4 * th];
            float4 d0  = *(const float4*)(xr);         // ve,vo for h=2th, 2th+1
            float4 d1  = *(const float4*)(xr + 128);   // ve,vo for h+64
            float4 tw0 = *(const float4*)(&Twid[w * 64 + q0]);
            float4 tw1 = *(const float4*)(&Twid[w * 64 + q0 + 4]);
            acc[0].x = fmaf(d0.x, tw0.x, acc[0].x); acc[0].y = fmaf(d0.x, tw0.y, acc[0].y);
            acc[0].z = fmaf(d0.y, tw0.z, acc[0].z); acc[0].w = fmaf(d0.y, tw0.w, acc[0].w);
            acc[1].x = fmaf(d0.x, tw1.x, acc[1].x); acc[1].y = fmaf(d0.x, tw1.y, acc[1].y);
            acc[1].z = fmaf(d0.y, tw1.z, acc[1].z); acc[1].w = fmaf(d0.y, tw1.w, acc[1].w);
            acc[2].x = fmaf(d0.z, tw0.x, acc[2].x); acc[2].y = fmaf(d0.z, tw0.y, acc[2].y);
            acc[2].z = fmaf(d0.w, tw0.z, acc[2].z); acc[2].w = fmaf(d0.w, tw0.w, acc[2].w);
            acc[3].x = fmaf(d0.z, tw1.x, acc[3].x); acc[3].y = fmaf(d0.z, tw1.y, acc[3].y);
            acc[3].z = fmaf(d0.w, tw1.z, acc[3].z); acc[3].w = fmaf(d0.w, tw1.w, acc[3].w);
            acc[4].x = fmaf(d1.x, tw0.x, acc[4].x); acc[4].y = fmaf(d1.x, tw0.y, acc[4].y);
            acc[4].z = fmaf(d1.y, tw0.z, acc[4].z); acc[4].w = fmaf(d1.y, tw0.w, acc[4].w);
            acc[5].x = fmaf(d1.x, tw1.x, acc[5].x); acc[5].y = fmaf(d1.x, tw1.y, acc[5].y);
            acc[5].z = fmaf(d1.y, tw1.z, acc[5].z); acc[5].w = fmaf(d1.y, tw1.w, acc[5].w);
            acc[6].x = fmaf(d1.z, tw0.x, acc[6].x); acc[6].y = fmaf(d1.z, tw0.y, acc[6].y);
            acc[6].z = fmaf(d1.w, tw0.z, acc[6].z); acc[6].w = fmaf(d1.w, tw0.w, acc[6].w);
            acc[7].x = fmaf(d1.z, tw1.x, acc[7].x); acc[7].y = fmaf(d1.z, tw1.y, acc[7].y);
            acc[7].z = fmaf(d1.w, tw1.z, acc[7].z); acc[7].w = fmaf(d1.w, tw1.w, acc[7].w);
        }
        __syncthreads();
        if (ph < 3) {
            writeR();
            __syncthreads();
        }
    }
    // In-register (h, h+64) fold -> Af planes, row stride 68.
    float* Af = smem;
    {
        int base = th * 68 + q0;
        *(float4*)(&Af[base])          = make_float4(acc[0].x+acc[4].x, acc[0].y+acc[4].y, acc[0].z+acc[4].z, acc[0].w+acc[4].w);
        *(float4*)(&Af[base + 4])      = make_float4(acc[1].x+acc[5].x, acc[1].y+acc[5].y, acc[1].z+acc[5].z, acc[1].w+acc[5].w);
        *(float4*)(&Af[2176 + base])   = make_float4(acc[0].x-acc[4].x, acc[0].y-acc[4].y, acc[0].z-acc[4].z, acc[0].w-acc[4].w);
        *(float4*)(&Af[2176 + base+4]) = make_float4(acc[1].x-acc[5].x, acc[1].y-acc[5].y, acc[1].z-acc[5].z, acc[1].w-acc[5].w);
        *(float4*)(&Af[4352 + base])   = make_float4(acc[2].x+acc[6].x, acc[2].y+acc[6].y, acc[2].z+acc[6].z, acc[2].w+acc[6].w);
        *(float4*)(&Af[4352 + base+4]) = make_float4(acc[3].x+acc[7].x, acc[3].y+acc[7].y, acc[3].z+acc[7].z, acc[3].w+acc[7].w);
        *(float4*)(&Af[6528 + base])   = make_float4(acc[2].x-acc[6].x, acc[2].y-acc[6].y, acc[2].z-acc[6].z, acc[2].w-acc[6].w);
        *(float4*)(&Af[6528 + base+4]) = make_float4(acc[3].x-acc[7].x, acc[3].y-acc[7].y, acc[3].z-acc[7].z, acc[3].w-acc[7].w);
    }
    __syncthreads();
    // ---- kB compute part (twiddles via rotation recurrence) ----
    {
        int k = t & 31, kxg = t >> 5;
        int kx0 = kxg * 4;
        int sig = k & 1;
        const float* pe = Af + sig * 2176;
        const float* po = Af + 4352 + sig * 2176;
        int a2 = (2 * k) & 127;
        float ca = tabs[a2], sa = tabs[129 + a2];
        float ce = 1.f, se = 0.f;
        float co_ = tabs[k], so_ = tabs[129 + k];
        float4 P1 = {0,0,0,0}, P2 = {0,0,0,0}, P3 = {0,0,0,0}, P4 = {0,0,0,0};
        for (int m = 0; m < 32; ++m) {
            float4 ae01 = *(const float4*)(pe + m * 68 + 2 * kx0);
            float4 ae23 = *(const float4*)(pe + m * 68 + 2 * kx0 + 4);
            float4 ao01 = *(const float4*)(po + m * 68 + 2 * kx0);
            float4 ao23 = *(const float4*)(po + m * 68 + 2 * kx0 + 4);
            P1.x = fmaf(ae01.x, ce, P1.x); P1.x = fmaf(ao01.x, co_, P1.x);
            P2.x = fmaf(ae01.y, se, P2.x); P2.x = fmaf(ao01.y, so_, P2.x);
            P3.x = fmaf(ae01.y, ce, P3.x); P3.x = fmaf(ao01.y, co_, P3.x);
            P4.x = fmaf(ae01.x, se, P4.x); P4.x = fmaf(ao01.x, so_, P4.x);
            P1.y = fmaf(ae01.z, ce, P1.y); P1.y = fmaf(ao01.z, co_, P1.y);
            P2.y = fmaf(ae01.w, se, P2.y); P2.y = fmaf(ao01.w, so_, P2.y);
            P3.y = fmaf(ae01.w, ce, P3.y); P3.y = fmaf(ao01.w, co_, P3.y);
            P4.y = fmaf(ae01.z, se, P4.y); P4.y = fmaf(ao01.z, so_, P4.y);
            P1.z = fmaf(ae23.x, ce, P1.z); P1.z = fmaf(ao23.x, co_, P1.z);
            P2.z = fmaf(ae23.y, se, P2.z); P2.z = fmaf(ao23.y, so_, P2.z);
            P3.z = fmaf(ae23.y, ce, P3.z); P3.z = fmaf(ao23.y, co_, P3.z);
            P4.z = fmaf(ae23.x, se, P4.z); P4.z = fmaf(ao23.x, so_, P4.z);
            P1.w = fmaf(ae23.z, ce, P1.w); P1.w = fmaf(ao23.z, co_, P1.w);
            P2.w = fmaf(ae23.w, se, P2.w); P2.w = fmaf(ao23.w, so_, P2.w);
            P3.w = fmaf(ae23.w, ce, P3.w); P3.w = fmaf(ao23.w, co_, P3.w);
            P4.w = fmaf(ae23.z, se, P4.w); P4.w = fmaf(ao23.z, so_, P4.w);
            float t1 = se * sa, t2 = ce * sa;
            float cen = fmaf(ce, ca, -t1);
            float sen = fmaf(se, ca, t2);
            ce = cen; se = sen;
            float t3 = so_ * sa, t4 = co_ * sa;
            float con = fmaf(co_, ca, -t3);
            float son = fmaf(so_, ca, t4);
            co_ = con; so_ = son;
        }
        float* xfb = XF + bc * 4096;
        *(float4*)(xfb + (k * 32 + kx0) * 2) =
            make_float4(P1.x + P2.x, P3.x - P4.x, P1.y + P2.y, P3.y - P4.y);
        *(float4*)(xfb + (k * 32 + kx0) * 2 + 4) =
            make_float4(P1.z + P2.z, P3.z - P4.z, P1.w + P2.w, P3.w - P4.w);
        if (k) {
            *(float4*)(xfb + ((64 - k) * 32 + kx0) * 2) =
                make_float4(P1.x - P2.x, P3.x + P4.x, P1.y - P2.y, P3.y + P4.y);
            *(float4*)(xfb + ((64 - k) * 32 + kx0) * 2 + 4) =
                make_float4(P1.z - P2.z, P3.z + P4.z, P1.w - P2.w, P3.w + P4.w);
        }
        if (t < 32) {
            int kx = t;
            float re = 0.f, im = 0.f;
            #pragma unroll 8
            for (int m = 0; m < 32; ++m) {
                float2 aep = *(const float2*)(&Af[       m * 68 + 2 * kx]);
                float2 aop = *(const float2*)(&Af[4352 + m * 68 + 2 * kx]);
                float sg = (m & 1) ? -1.f : 1.f;
                re = fmaf(sg, aep.x - aop.y, re);
                im = fmaf(sg, aep.y + aop.x, im);
            }
            xfb[(32 * 32 + kx) * 2]     = re;
            xfb[(32 * 32 + kx) * 2 + 1] = im;
        }
    }
}

// ---- kC v8: full-line W streaming + my-fastest block order ----------------
__global__ __launch_bounds__(256) void kC(const float* __restrict__ XF,
                                          const float* __restrict__ Wgt,
                                          float* __restrict__ YF0,
                                          float* __restrict__ YF1) {
    __shared__ __align__(16) float Xb[2][4096];  // [buf][ci_l 4][b 16][mx 32] cplx
    __shared__ __align__(16) float Wb[2][2048];  // [buf][pl 2][ci_l 4][co_l 8][mx 32]
    int t = threadIdx.x;
    int lane = t & 63, wid = t >> 6;
    int bid = blockIdx.x;
    int my  = bid & 31;
    int cih = (bid >> 5) & 1;
    int cot = (bid >> 6) & 7;
    int c   = bid >> 9;
    int co0 = cot * 8;
    int slotbase = (c * 32 + my) * 32;  // + mx
    int mx   = t & 31;
    int co_l = t >> 5;
    int co = co0 + co_l;
    int ci0 = cih * 32;
    float2 acc[16];
    #pragma unroll
    for (int i = 0; i < 16; ++i) acc[i] = make_float2(0.f, 0.f);
    const float* wbase = Wgt + (size_t)c * 4194304 + (size_t)my * 32;
    auto stage = [&](int cc, int buf) {
        #pragma unroll
        for (int i = 0; i < 4; ++i) {
            int inst = wid * 4 + i;
            int u = inst * 64 + lane;             // [ci_l 4][b 16][mxp 16]
            int mxp = u & 15, b = (u >> 4) & 15, ci_l = u >> 8;
            int ci = ci0 + cc * 4 + ci_l;
            const float* g = XF + ((size_t)(b * 64 + ci) * 2048 + slotbase + mxp * 2) * 2;
            float* l = Xb[buf] + inst * 256;
            __builtin_amdgcn_global_load_lds(g, l, 16, 0, 0);
        }
        #pragma unroll
        for (int i = 0; i < 2; ++i) {
            int inst = wid * 2 + i;
            int u = inst * 64 + lane;             // [pl 2][ci_l 4][co_l 8][mx4 8]
            int mx4 = u & 7, col = (u >> 3) & 7, ci_l = (u >> 6) & 3, pl = u >> 8;
            const float* g = wbase + (size_t)pl * 8388608
                           + ((size_t)(ci0 + cc * 4 + ci_l) * 64 + co0 + col) * 1024
                           + mx4 * 4;
            float* l = Wb[buf] + inst * 256;
            __builtin_amdgcn_global_load_lds(g, l, 16, 0, 0);
        }
    };
#define KC_COMPUTE(BUF)                                                      \
    {                                                                        \
        _Pragma("unroll")                                                    \
        for (int j = 0; j < 4; ++j) {                                        \
            float wre = Wb[BUF][(j * 8 + co_l) * 32 + mx];                   \
            float wim = Wb[BUF][1024 + (j * 8 + co_l) * 32 + mx];            \
            _Pragma("unroll")                                                \
            for (int b = 0; b < 16; ++b) {                                   \
                float2 xv = *(const float2*)(&Xb[BUF][((j * 16 + b) * 32 + mx) * 2]); \
                acc[b].x = fmaf(xv.x, wre, acc[b].x);                        \
                acc[b].x = fmaf(-xv.y, wim, acc[b].x);                       \
                acc[b].y = fmaf(xv.x, wim, acc[b].y);                        \
                acc[b].y = fmaf(xv.y, wre, acc[b].y);                        \
            }                                                                \
        }                                                                    \
    }
    stage(0, 0);
    __syncthreads();
    stage(1, 1); KC_COMPUTE(0); __syncthreads();
    stage(2, 0); KC_COMPUTE(1); __syncthreads();
    stage(3, 1); KC_COMPUTE(0); __syncthreads();
    stage(4, 0); KC_COMPUTE(1); __syncthreads();
    stage(5, 1); KC_COMPUTE(0); __syncthreads();
    stage(6, 0); KC_COMPUTE(1); __syncthreads();
    stage(7, 1); KC_COMPUTE(0); __syncthreads();
    KC_COMPUTE(1);
#undef KC_COMPUTE
    float* YF = cih ? YF1 : YF0;
    #pragma unroll
    for (int b = 0; b < 16; ++b) {
        *(float2*)(YF + ((size_t)(b * 64 + co) * 2048 + slotbase + mx) * 2) = acc[b];
    }
}

// ---- kDE v2: inv H-DFT + inv W-rDFT, all twiddles via phasor recurrence ---
// One block per bo. LDS = U (Q/R -> Zt) only, ~34 KB -> 4 blocks/CU.
__global__ __launch_bounds__(256) void kDE(const float* __restrict__ YF0,
                                           const float* __restrict__ YF1,
                                           const float* __restrict__ bias,
                                           float* __restrict__ out) {
    __shared__ float tabs[258];
    __shared__ __align__(16) float U[8448];   // Q[0,2112)+R[2112,4224) -> Zt[64][132]
    build_tab(tabs);
    __syncthreads();
    int t = threadIdx.x;
    size_t bo = blockIdx.x;
    const float inv = 6.103515625e-05f;  // 1/16384
    float* Qs = U;
    float* Rs = U + 2112;
    const float* y0 = YF0 + bo * 4096;
    const float* y1 = YF1 + bo * 4096;
    for (int u = t; u < 528; u += 256) {
        int k = u >> 4, kxf = (u & 15) * 4;
        float4 a0 = *(const float4*)(y0 + k * 64 + kxf);
        float4 a1 = *(const float4*)(y1 + k * 64 + kxf);
        float4 a = make_float4(a0.x+a1.x, a0.y+a1.y, a0.z+a1.z, a0.w+a1.w);
        float4 Q, R;
        if (k == 0) { Q = a; R = make_float4(0.f, 0.f, 0.f, 0.f); }
        else if (k == 32) { Q = a; R = make_float4(-a.x, -a.y, -a.z, -a.w); }
        else {
            float4 b0 = *(const float4*)(y0 + (64 - k) * 64 + kxf);
            float4 b1 = *(const float4*)(y1 + (64 - k) * 64 + kxf);
            float4 bb = make_float4(b0.x+b1.x, b0.y+b1.y, b0.z+b1.z, b0.w+b1.w);
            Q = make_float4(a.x+bb.x, a.y+bb.y, a.z+bb.z, a.w+bb.w);
            R = make_float4(a.x-bb.x, a.y-bb.y, a.z-bb.z, a.w-bb.w);
        }
        *(float4*)(&Qs[k * 64 + kxf]) = Q;
        *(float4*)(&Rs[k * 64 + kxf]) = R;
    }
    __syncthreads();
    int hh = t >> 2;
    int kx0 = (t & 3) * 8;
    float4 Ee0 = {0,0,0,0}, Ee1 = {0,0,0,0}, Ee2 = {0,0,0,0}, Ee3 = {0,0,0,0};
    float4 Eo0 = {0,0,0,0}, Eo1 = {0,0,0,0}, Eo2 = {0,0,0,0}, Eo3 = {0,0,0,0};
    // phasor: (cph, sph) = e^{i*kk*hh*theta}, rotated by (cad, sad) per body
    float cad = tabs[hh], sad = tabs[129 + hh];
    float cph = 1.f, sph = 0.f;
#define KD_ROT() { float cn = fmaf(cph, cad, -(sph * sad));                  \
                   float sn = fmaf(sph, cad, cph * sad); cph = cn; sph = sn; }
#define KD_BODY(E0, E1, E2, E3, kk)                                          \
    {                                                                        \
        float c = cph, s = sph;                                              \
        const float4* Qp = (const float4*)(&Qs[(kk) * 64 + kx0 * 2]);        \
        const float4* Rp = (const float4*)(&Rs[(kk) * 64 + kx0 * 2]);        \
        float4 Qv, Rv;                                                       \
        Qv = Qp[0]; Rv = Rp[0];                                              \
        E0.x = fmaf(c, Qv.x, E0.x); E0.x = fmaf(-s, Rv.y, E0.x);             \
        E0.y = fmaf(c, Qv.y, E0.y); E0.y = fmaf(s, Rv.x, E0.y);              \
        E0.z = fmaf(c, Qv.z, E0.z); E0.z = fmaf(-s, Rv.w, E0.z);             \
        E0.w = fmaf(c, Qv.w, E0.w); E0.w = fmaf(s, Rv.z, E0.w);              \
        Qv = Qp[1]; Rv = Rp[1];                                              \
        E1.x = fmaf(c, Qv.x, E1.x); E1.x = fmaf(-s, Rv.y, E1.x);             \
        E1.y = fmaf(c, Qv.y, E1.y); E1.y = fmaf(s, Rv.x, E1.y);              \
        E1.z = fmaf(c, Qv.z, E1.z); E1.z = fmaf(-s, Rv.w, E1.z);             \
        E1.w = fmaf(c, Qv.w, E1.w); E1.w = fmaf(s, Rv.z, E1.w);              \
        Qv = Qp[2]; Rv = Rp[2];                                              \
        E2.x = fmaf(c, Qv.x, E2.x); E2.x = fmaf(-s, Rv.y, E2.x);             \
        E2.y = fmaf(c, Qv.y, E2.y); E2.y = fmaf(s, Rv.x, E2.y);              \
        E2.z = fmaf(c, Qv.z, E2.z); E2.z = fmaf(-s, Rv.w, E2.z);             \
        E2.w = fmaf(c, Qv.w, E2.w); E2.w = fmaf(s, Rv.z, E2.w);              \
        Qv = Qp[3]; Rv = Rp[3];                                              \
        E3.x = fmaf(c, Qv.x, E3.x); E3.x = fmaf(-s, Rv.y, E3.x);             \
        E3.y = fmaf(c, Qv.y, E3.y); E3.y = fmaf(s, Rv.x, E3.y);              \
        E3.z = fmaf(c, Qv.z, E3.z); E3.z = fmaf(-s, Rv.w, E3.z);             \
        E3.w = fmaf(c, Qv.w, E3.w); E3.w = fmaf(s, Rv.z, E3.w);              \
        KD_ROT();                                                            \
    }
    #pragma unroll 4
    for (int u = 0; u < 16; ++u) {
        KD_BODY(Ee0, Ee1, Ee2, Ee3, 2 * u);
        KD_BODY(Eo0, Eo1, Eo2, Eo3, 2 * u + 1);
    }
    KD_BODY(Ee0, Ee1, Ee2, Ee3, 32);
#undef KD_BODY
#undef KD_ROT
    __syncthreads();  // all Q/R reads done -> reuse U as Zt
    float* Zt = U;    // [q][h], stride 132
    {
        float* zr = &Zt[(2 * kx0) * 132 + hh];        // row hh
        float* zs = zr + 64;                          // row hh+64
        zr[0*132]  = Ee0.x + Eo0.x;  zs[0*132]  = Ee0.x - Eo0.x;
        zr[1*132]  = Ee0.y + Eo0.y;  zs[1*132]  = Ee0.y - Eo0.y;
        zr[2*132]  = Ee0.z + Eo0.z;  zs[2*132]  = Ee0.z - Eo0.z;
        zr[3*132]  = Ee0.w + Eo0.w;  zs[3*132]  = Ee0.w - Eo0.w;
        zr[4*132]  = Ee1.x + Eo1.x;  zs[4*132]  = Ee1.x - Eo1.x;
        zr[5*132]  = Ee1.y + Eo1.y;  zs[5*132]  = Ee1.y - Eo1.y;
        zr[6*132]  = Ee1.z + Eo1.z;  zs[6*132]  = Ee1.z - Eo1.z;
        zr[7*132]  = Ee1.w + Eo1.w;  zs[7*132]  = Ee1.w - Eo1.w;
        zr[8*132]  = Ee2.x + Eo2.x;  zs[8*132]  = Ee2.x - Eo2.x;
        zr[9*132]  = Ee2.y + Eo2.y;  zs[9*132]  = Ee2.y - Eo2.y;
        zr[10*132] = Ee2.z + Eo2.z;  zs[10*132] = Ee2.z - Eo2.z;
        zr[11*132] = Ee2.w + Eo2.w;  zs[11*132] = Ee2.w - Eo2.w;
        zr[12*132] = Ee3.x + Eo3.x;  zs[12*132] = Ee3.x - Eo3.x;
        zr[13*132] = Ee3.y + Eo3.y;  zs[13*132] = Ee3.y - Eo3.y;
        zr[14*132] = Ee3.z + Eo3.z;  zs[14*132] = Ee3.z - Eo3.z;
        zr[15*132] = Ee3.w + Eo3.w;  zs[15*132] = Ee3.w - Eo3.w;
    }
    __syncthreads();
    // kE GEMM w-folded; Ts eliminated via dual phasors per thread.
    int w0 = (t & 31) * 2;
    int h0 = (t >> 5) * 16;
    float2 We[16], Wo[16];
    #pragma unroll
    for (int j = 0; j < 16; ++j) { We[j] = make_float2(0.f, 0.f); Wo[j] = make_float2(0.f, 0.f); }
    float caA = tabs[w0],     saA = tabs[129 + w0];
    float caB = tabs[w0 + 1], saB = tabs[129 + w0 + 1];
    float cA = 1.f, sA = 0.f, cB = 1.f, sB = 0.f;
    const float twoinv = 2.f * inv;
#define KE_ROT() { float cn = fmaf(cA, caA, -(sA * saA));                      \
                   float sn = fmaf(sA, caA, cA * saA); cA = cn; sA = sn;       \
                   cn = fmaf(cB, caB, -(sB * saB));                            \
                   sn = fmaf(sB, caB, cB * saB); cB = cn; sB = sn; }
#define KE_BODY(E, K, TEX, TEY, TOX, TOY)                                      \
    {                                                                          \
        const float4* zpe = (const float4*)(&Zt[(2*(K)) * 132 + h0]);          \
        const float4* zpo = (const float4*)(&Zt[(2*(K)+1) * 132 + h0]);        \
        float tex = (TEX), tey = (TEY), tox = (TOX), toy = (TOY);              \
        float4 e0 = zpe[0], e1 = zpe[1], e2 = zpe[2], e3 = zpe[3];             \
        float4 o0 = zpo[0], o1 = zpo[1], o2 = zpo[2], o3 = zpo[3];             \
        E[0].x  = fmaf(e0.x, tex, E[0].x);  E[0].x  = fmaf(o0.x, tox, E[0].x);   \
        E[0].y  = fmaf(e0.x, tey, E[0].y);  E[0].y  = fmaf(o0.x, toy, E[0].y);   \
        E[1].x  = fmaf(e0.y, tex, E[1].x);  E[1].x  = fmaf(o0.y, tox, E[1].x);   \
        E[1].y  = fmaf(e0.y, tey, E[1].y);  E[1].y  = fmaf(o0.y, toy, E[1].y);   \
        E[2].x  = fmaf(e0.z, tex, E[2].x);  E[2].x  = fmaf(o0.z, tox, E[2].x);   \
        E[2].y  = fmaf(e0.z, tey, E[2].y);  E[2].y  = fmaf(o0.z, toy, E[2].y);   \
        E[3].x  = fmaf(e0.w, tex, E[3].x);  E[3].x  = fmaf(o0.w, tox, E[3].x);   \
        E[3].y  = fmaf(e0.w, tey, E[3].y);  E[3].y  = fmaf(o0.w, toy, E[3].y);   \
        E[4].x  = fmaf(e1.x, tex, E[4].x);  E[4].x  = fmaf(o1.x, tox, E[4].x);   \
        E[4].y  = fmaf(e1.x, tey, E[4].y);  E[4].y  = fmaf(o1.x, toy, E[4].y);   \
        E[5].x  = fmaf(e1.y, tex, E[5].x);  E[5].x  = fmaf(o1.y, tox, E[5].x);   \
        E[5].y  = fmaf(e1.y, tey, E[5].y);  E[5].y  = fmaf(o1.y, toy, E[5].y);   \
        E[6].x  = fmaf(e1.z, tex, E[6].x);  E[6].x  = fmaf(o1.z, tox, E[6].x);   \
        E[6].y  = fmaf(e1.z, tey, E[6].y);  E[6].y  = fmaf(o1.z, toy, E[6].y);   \
        E[7].x  = fmaf(e1.w, tex, E[7].x);  E[7].x  = fmaf(o1.w, tox, E[7].x);   \
        E[7].y  = fmaf(e1.w, tey, E[7].y);  E[7].y  = fmaf(o1.w, toy, E[7].y);   \
        E[8].x  = fmaf(e2.x, tex, E[8].x);  E[8].x  = fmaf(o2.x, tox, E[8].x);   \
        E[8].y  = fmaf(e2.x, tey, E[8].y);  E[8].y  = fmaf(o2.x, toy, E[8].y);   \
        E[9].x  = fmaf(e2.y, tex, E[9].x);  E[9].x  = fmaf(o2.y, tox, E[9].x);   \
        E[9].y  = fmaf(e2.y, tey, E[9].y);  E[9].y  = fmaf(o2.y, toy, E[9].y);   \
        E[10].x = fmaf(e2.z, tex, E[10].x); E[10].x = fmaf(o2.z, tox, E[10].x);  \
        E[10].y = fmaf(e2.z, tey, E[10].y); E[10].y = fmaf(o2.z, toy, E[10].y);  \
        E[11].x = fmaf(e2.w, tex, E[11].x); E[11].x = fmaf(o2.w, tox, E[11].x);  \
        E[11].y = fmaf(e2.w, tey, E[11].y); E[11].y = fmaf(o2.w, toy, E[11].y);  \
        E[12].x = fmaf(e3.x, tex, E[12].x); E[12].x = fmaf(o3.x, tox, E[12].x);  \
        E[12].y = fmaf(e3.x, tey, E[12].y); E[12].y = fmaf(o3.x, toy, E[12].y);  \
        E[13].x = fmaf(e3.y, tex, E[13].x); E[13].x = fmaf(o3.y, tox, E[13].x);  \
        E[13].y = fmaf(e3.y, tey, E[13].y); E[13].y = fmaf(o3.y, toy, E[13].y);  \
        E[14].x = fmaf(e3.z, tex, E[14].x); E[14].x = fmaf(o3.z, tox, E[14].x);  \
        E[14].y = fmaf(e3.z, tey, E[14].y); E[14].y = fmaf(o3.z, toy, E[14].y);  \
        E[15].x = fmaf(e3.w, tex, E[15].x); E[15].x = fmaf(o3.w, tox, E[15].x);  \
        E[15].y = fmaf(e3.w, tey, E[15].y); E[15].y = fmaf(o3.w, toy, E[15].y);  \
    }
    // k = 0: Ts[0][w] = inv, Ts[1][w] = 0
    KE_BODY(We, 0, inv, inv, 0.f, 0.f);
    KE_ROT();  // phase -> k=1
    #pragma unroll 3
    for (int u = 0; u < 15; ++u) {
        KE_BODY(Wo, 2*u+1, twoinv*cA, twoinv*cB, -twoinv*sA, -twoinv*sB);
        KE_ROT();
        KE_BODY(We, 2*u+2, twoinv*cA, twoinv*cB, -twoinv*sA, -twoinv*sB);
        KE_ROT();
    }
    KE_BODY(Wo, 31, twoinv*cA, twoinv*cB, -twoinv*sA, -twoinv*sB);
#undef KE_BODY
#undef KE_ROT
    float bv = bias[(int)(bo & 63)];
    float* ob = out + ((size_t)(bo * 128 + h0)) * 128;
    #pragma unroll
    for (int j = 0; j < 16; ++j) {
        float2 lo = make_float2(We[j].x + Wo[j].x + bv, We[j].y + Wo[j].y + bv);
        float2 hi = make_float2(We[j].x - Wo[j].x + bv, We[j].y - Wo[j].y + bv);
        *(float2*)(ob + (size_t)j * 128 + w0)      = lo;
        *(float2*)(ob + (size_t)j * 128 + w0 + 64) = hi;
    }
}

extern "C" void kernel_launch(void* const* d_in, const int* in_sizes, int n_in,
                              void* d_out, int out_size, void* d_ws, size_t ws_size,
                              hipStream_t stream) {
    (void)in_sizes; (void)n_in; (void)out_size; (void)ws_size;
    const float* x    = (const float*)d_in[0];
    const float* wgt  = (const float*)d_in[1];
    const float* bias = (const float*)d_in[2];
    float* outp   = (float*)d_out;
    char* ws = (char*)d_ws;
    float* bufXF  = (float*)(ws + (48u << 20));     // [48, 64 MiB)
    float* bufYF0 = (float*)(ws);                   // [0, 16 MiB)
    float* bufYF1 = (float*)(ws + (16u << 20));     // [16, 32 MiB)
    hipLaunchKernelGGL(kAB, dim3(1024), dim3(256), 0, stream, x, bufXF);
    hipLaunchKernelGGL(kC, dim3(1024), dim3(256), 0, stream, bufXF, wgt, bufYF0, bufYF1);
    hipLaunchKernelGGL(kDE, dim3(1024), dim3(256), 0, stream, bufYF0, bufYF1, bias, outp);
}